// Round 12
// baseline (513.006 us; speedup 1.0000x reference)
//
#include <hip/hip_runtime.h>

// ---------------------------------------------------------------------------
// EntropyCalculator: 2-layer post-norm transformer encoder + entropy head.
// B=256 S=512 D=128 H=4 HD=32 FF=512 V=256
// Fused QKV+attention (setprio'd); fused oproj+LN1+FFN+LN2 (block_tail);
// register-transposed vocab/entropy.
// ---------------------------------------------------------------------------

typedef __bf16 bf16x8 __attribute__((ext_vector_type(8)));
typedef float  f32x4  __attribute__((ext_vector_type(4)));

__device__ __forceinline__ unsigned short f2bf(float f) {
  union { float f; unsigned int u; } c; c.f = f;
  unsigned int u = c.u;
  u += 0x7FFFu + ((u >> 16) & 1u);   // round-to-nearest-even
  return (unsigned short)(u >> 16);
}
__device__ __forceinline__ float bf2f(unsigned short u) {
  union { unsigned int u; float f; } c; c.u = ((unsigned int)u) << 16;
  return c.f;
}

__device__ __forceinline__ float EXP2(float x) {
#if __has_builtin(__builtin_amdgcn_exp2f)
  return __builtin_amdgcn_exp2f(x);
#else
  return exp2f(x);
#endif
}

__device__ __forceinline__ unsigned int cvtpk_bf16(float lo, float hi) {
  unsigned int r;
  asm("v_cvt_pk_bf16_f32 %0, %1, %2" : "=v"(r) : "v"(lo), "v"(hi));
  return r;
}
__device__ __forceinline__ void plswap32(unsigned int& a, unsigned int& b) {
  asm("v_permlane32_swap_b32 %0, %1" : "+v"(a), "+v"(b));
}
__device__ __forceinline__ void plswap16(unsigned int& a, unsigned int& b) {
  asm("v_permlane16_swap_b32 %0, %1" : "+v"(a), "+v"(b));
}
// Merge two mfma outputs (rows 0..15 / 16..31 on g*4+reg, col on c) into an
// operand frag: lane(c,g) = M[idx=c][32-dim packed g*8..g*8+7].
__device__ __forceinline__ bf16x8 packfrag(f32x4 a, f32x4 b) {
  unsigned int w00 = cvtpk_bf16(a[0], a[1]), w01 = cvtpk_bf16(a[2], a[3]);
  unsigned int w10 = cvtpk_bf16(b[0], b[1]), w11 = cvtpk_bf16(b[2], b[3]);
  plswap32(w00, w10); plswap16(w00, w10);
  plswap32(w01, w11); plswap16(w01, w11);
  union { unsigned int u[4]; bf16x8 v; } pk;
  pk.u[0] = w00; pk.u[1] = w01; pk.u[2] = w10; pk.u[3] = w11;
  return pk.v;
}

#define MFMA __builtin_amdgcn_mfma_f32_16x16x32_bf16

// ---------------------------------------------------------------------------
// weight conversions
// ---------------------------------------------------------------------------
__global__ void conv_permA(const float* __restrict__ src,
                           unsigned short* __restrict__ dst, int K, int n) {
  int i = blockIdx.x * 256 + threadIdx.x;
  if (i >= n) return;
  int row = i / K, k = i - row * K;
  int frag = (row >> 4) * (K >> 5) + (k >> 5);
  int d = frag * 512 + ((k >> 3) & 3) * 128 + (row & 15) * 8 + (k & 7);
  dst[d] = f2bf(src[i]);
}

// attn_w [2][384][128] -> per (layer, head, mat q/k/v) A-frag arrays of
// 2 db x 4 kk frags (4096 hw each).  Q rows pre-scaled.
#define QSCALE 0.2550602989892646f
__global__ void conv_attn_headA(const float* __restrict__ src,
                                unsigned short* __restrict__ dst) {
  int i = blockIdx.x * 256 + threadIdx.x;  // 98304
  int l = i / 49152, rem = i - l * 49152;
  int row = rem >> 7, k = rem & 127;
  int mat = row >> 7;            // 0=q 1=k 2=v
  int head = (row >> 5) & 3;
  int dr = row & 31;
  float v = src[i];
  if (mat == 0) v *= QSCALE;
  int d = ((l * 4 + head) * 3 + mat) * 4096 +
          ((dr >> 4) * 4 + (k >> 5)) * 512 + ((k >> 3) & 3) * 128 +
          (dr & 15) * 8 + (k & 7);
  dst[d] = f2bf(v);
}
__global__ void conv_attn_b(const float* __restrict__ src,
                            float* __restrict__ dst) {
  int i = blockIdx.x * 256 + threadIdx.x;  // 768
  if (i < 768) {
    float v = src[i];
    if ((i % 384) < 128) v *= QSCALE;
    dst[i] = v;
  }
}

// ---------------------------------------------------------------------------
// Embedding + LayerNorm -> bf16 residual stream.  One wave per token.
// ---------------------------------------------------------------------------
__global__ __launch_bounds__(256) void embed_ln(
    const int* __restrict__ bytes, const float* __restrict__ emb,
    const float* __restrict__ pos, const float* __restrict__ g,
    const float* __restrict__ bta, unsigned short* __restrict__ hbf) {
  int wv = threadIdx.x >> 6, lane = threadIdx.x & 63;
  int tok = blockIdx.x * 4 + wv;
  int s = tok & 511;
  int bidx = bytes[tok];
  const float* e = emb + (size_t)bidx * 128;
  const float* p = pos + (size_t)s * 128;
  float x0 = e[lane] + p[lane];
  float x1 = e[lane + 64] + p[lane + 64];
  float sum = x0 + x1, ssq = x0 * x0 + x1 * x1;
#pragma unroll
  for (int off = 32; off; off >>= 1) {
    sum += __shfl_xor(sum, off);
    ssq += __shfl_xor(ssq, off);
  }
  float mean = sum * 0.0078125f;
  float var = ssq * 0.0078125f - mean * mean;
  float rs = rsqrtf(var + 1e-5f);
  float y0 = (x0 - mean) * rs * g[lane] + bta[lane];
  float y1 = (x1 - mean) * rs * g[lane + 64] + bta[lane + 64];
  size_t o = (size_t)tok * 128;
  hbf[o + lane] = f2bf(y0); hbf[o + lane + 64] = f2bf(y1);
}

// ---------------------------------------------------------------------------
// Fused QKV + flash attention (round-11 structure + s_setprio).
// One block (512 thr = 8 waves) per (b, head).
// ---------------------------------------------------------------------------
__global__ __launch_bounds__(512)
__attribute__((amdgpu_waves_per_eu(4, 4))) void attn_fused(
    const unsigned short* __restrict__ h, const unsigned short* __restrict__ Wa,
    const float* __restrict__ ab, unsigned short* __restrict__ obf) {
  __shared__ __bf16 Ks[32 * 512];
  __shared__ __bf16 Vt[32 * 512];

  const int hh = blockIdx.x & 3, bl = blockIdx.x >> 2;
  const int t = threadIdx.x;
  const int lane = t & 63, wv = t >> 6;
  const int c = lane & 15, g = lane >> 4;
  const size_t tok0 = (size_t)bl * 512;
  const size_t myq = tok0 + wv * 64;

  const unsigned short* Wb = Wa + hh * 3 * 4096;
  const float* bq = ab + hh * 32;
  const float* bk = ab + 128 + hh * 32;
  const float* bv = ab + 256 + hh * 32;

  bf16x8 qb[4];
  f32x4 dv[2][2];
#pragma unroll
  for (int tf = 0; tf < 4; ++tf) {
    bf16x8 a4[4];
#pragma unroll
    for (int kk = 0; kk < 4; ++kk)
      a4[kk] =
          *(const bf16x8*)(h + (myq + tf * 16 + c) * 128 + kk * 32 + g * 8);
    // ---- Q ----
    {
      f32x4 d0 = {}, d1 = {};
#pragma unroll
      for (int kk = 0; kk < 4; ++kk) {
        d0 = MFMA(*(const bf16x8*)(Wb + kk * 512 + lane * 8), a4[kk], d0,
                  0, 0, 0);
        d1 = MFMA(*(const bf16x8*)(Wb + (4 + kk) * 512 + lane * 8), a4[kk],
                  d1, 0, 0, 0);
      }
      float4 b0 = *(const float4*)(bq + g * 4);
      float4 b1 = *(const float4*)(bq + 16 + g * 4);
      d0[0] += b0.x; d0[1] += b0.y; d0[2] += b0.z; d0[3] += b0.w;
      d1[0] += b1.x; d1[1] += b1.y; d1[2] += b1.z; d1[3] += b1.w;
      qb[tf] = packfrag(d0, d1);
    }
    // ---- K ----
    {
      f32x4 d0 = {}, d1 = {};
#pragma unroll
      for (int kk = 0; kk < 4; ++kk) {
        d0 = MFMA(*(const bf16x8*)(Wb + 4096 + kk * 512 + lane * 8), a4[kk],
                  d0, 0, 0, 0);
        d1 = MFMA(*(const bf16x8*)(Wb + 4096 + (4 + kk) * 512 + lane * 8),
                  a4[kk], d1, 0, 0, 0);
      }
      float4 b0 = *(const float4*)(bk + g * 4);
      float4 b1 = *(const float4*)(bk + 16 + g * 4);
      d0[0] += b0.x; d0[1] += b0.y; d0[2] += b0.z; d0[3] += b0.w;
      d1[0] += b1.x; d1[1] += b1.y; d1[2] += b1.z; d1[3] += b1.w;
      *(bf16x8*)&Ks[(wv * 4 + tf) * 512 + lane * 8] = packfrag(d0, d1);
    }
    // ---- V ----
#pragma unroll
    for (int hf = 0; hf < 2; ++hf) {
      f32x4 tv = {};
#pragma unroll
      for (int kk = 0; kk < 4; ++kk)
        tv = MFMA(a4[kk],
                  *(const bf16x8*)(Wb + 8192 + (hf * 4 + kk) * 512 + lane * 8),
                  tv, 0, 0, 0);
      float bvv = bv[hf * 16 + c];
      tv[0] += bvv; tv[1] += bvv; tv[2] += bvv; tv[3] += bvv;
      dv[tf & 1][hf] = tv;
    }
    if (tf & 1) {
#pragma unroll
      for (int hf = 0; hf < 2; ++hf)
        *(bf16x8*)&Vt[(hf * 16 + wv * 2 + (tf >> 1)) * 512 + lane * 8] =
            packfrag(dv[0][hf], dv[1][hf]);
    }
  }
  __syncthreads();

  f32x4 ot[4][2] = {};
  float l[4] = {0.f, 0.f, 0.f, 0.f};
  const f32x4 zz = {0.f, 0.f, 0.f, 0.f};

  for (int kt = 0; kt < 8; ++kt) {
    bf16x8 ka[4];
#pragma unroll
    for (int kf = 0; kf < 4; ++kf)
      ka[kf] = *(const bf16x8*)&Ks[(kt * 4 + kf) * 512 + lane * 8];
    bf16x8 vb2[2][2];
#pragma unroll
    for (int hf = 0; hf < 2; ++hf)
#pragma unroll
      for (int ksl = 0; ksl < 2; ++ksl)
        vb2[hf][ksl] =
            *(const bf16x8*)&Vt[(hf * 16 + kt * 2 + ksl) * 512 + lane * 8];

#pragma unroll
    for (int qf = 0; qf < 4; ++qf) {
      __builtin_amdgcn_s_setprio(1);
      f32x4 sA = MFMA(ka[0], qb[qf], zz, 0, 0, 0);
      f32x4 sB = MFMA(ka[1], qb[qf], zz, 0, 0, 0);
      f32x4 sC = MFMA(ka[2], qb[qf], zz, 0, 0, 0);
      f32x4 sD = MFMA(ka[3], qb[qf], zz, 0, 0, 0);
      __builtin_amdgcn_s_setprio(0);

      {
        float pa0 = EXP2(sA[0]), pa1 = EXP2(sA[1]);
        float pa2 = EXP2(sA[2]), pa3 = EXP2(sA[3]);
        float pb0 = EXP2(sB[0]), pb1 = EXP2(sB[1]);
        float pb2 = EXP2(sB[2]), pb3 = EXP2(sB[3]);
        l[qf] += ((pa0 + pa1) + (pa2 + pa3)) + ((pb0 + pb1) + (pb2 + pb3));
        f32x4 pa = {pa0, pa1, pa2, pa3};
        f32x4 pb = {pb0, pb1, pb2, pb3};
        bf16x8 pk = packfrag(pa, pb);
        __builtin_amdgcn_s_setprio(1);
        ot[qf][0] = MFMA(vb2[0][0], pk, ot[qf][0], 0, 0, 0);
        ot[qf][1] = MFMA(vb2[1][0], pk, ot[qf][1], 0, 0, 0);
        __builtin_amdgcn_s_setprio(0);
      }
      {
        float pa0 = EXP2(sC[0]), pa1 = EXP2(sC[1]);
        float pa2 = EXP2(sC[2]), pa3 = EXP2(sC[3]);
        float pb0 = EXP2(sD[0]), pb1 = EXP2(sD[1]);
        float pb2 = EXP2(sD[2]), pb3 = EXP2(sD[3]);
        l[qf] += ((pa0 + pa1) + (pa2 + pa3)) + ((pb0 + pb1) + (pb2 + pb3));
        f32x4 pa = {pa0, pa1, pa2, pa3};
        f32x4 pb = {pb0, pb1, pb2, pb3};
        bf16x8 pk = packfrag(pa, pb);
        __builtin_amdgcn_s_setprio(1);
        ot[qf][0] = MFMA(vb2[0][1], pk, ot[qf][0], 0, 0, 0);
        ot[qf][1] = MFMA(vb2[1][1], pk, ot[qf][1], 0, 0, 0);
        __builtin_amdgcn_s_setprio(0);
      }
    }
  }

#pragma unroll
  for (int qf = 0; qf < 4; ++qf) {
    l[qf] += __shfl_xor(l[qf], 16);
    l[qf] += __shfl_xor(l[qf], 32);
  }
#pragma unroll
  for (int qf = 0; qf < 4; ++qf) {
    float rl = 1.0f / l[qf];
#pragma unroll
    for (int hf = 0; hf < 2; ++hf) {
      ushort4 pk;
      pk.x = f2bf(ot[qf][hf][0] * rl);
      pk.y = f2bf(ot[qf][hf][1] * rl);
      pk.z = f2bf(ot[qf][hf][2] * rl);
      pk.w = f2bf(ot[qf][hf][3] * rl);
      *(ushort4*)(obf + (myq + qf * 16 + c) * 128 + hh * 32 + hf * 16 +
                  g * 4) = pk;
    }
  }
}

// ---------------------------------------------------------------------------
// Fused block tail: out-proj + residual + LN1 + FFN + residual + LN2,
// all register-resident between the two LNs.  256 thr = 4 waves,
// wave owns 32 tokens.  LN1 output kept as (a) packed bf16 residual ybf,
// (b) FFN B-operand frags at2 via packfrag.  In-place on h.
// ---------------------------------------------------------------------------
__global__ __launch_bounds__(256, 3) void block_tail(
    const unsigned short* __restrict__ A,    // attention output (obf)
    const unsigned short* __restrict__ Wo, const float* __restrict__ bo,
    const float* __restrict__ g1, const float* __restrict__ b1n,
    const unsigned short* __restrict__ W1p, const float* __restrict__ b1,
    const unsigned short* __restrict__ W2p, const float* __restrict__ b2,
    const float* __restrict__ g2, const float* __restrict__ b2n,
    unsigned short* __restrict__ h) {
  const int lane = threadIdx.x & 63, w = threadIdx.x >> 6;
  const int c = lane & 15, g = lane >> 4;
  const size_t tok0 = (size_t)blockIdx.x * 128 + w * 32;

  // ---- out-proj ----
  f32x4 acc[8][2] = {};
  {
    bf16x8 at[2][4];
#pragma unroll
    for (int tf = 0; tf < 2; ++tf)
#pragma unroll
      for (int kk = 0; kk < 4; ++kk)
        at[tf][kk] =
            *(const bf16x8*)(A + (tok0 + tf * 16 + c) * 128 + kk * 32 + g * 8);
#pragma unroll
    for (int db = 0; db < 8; ++db)
#pragma unroll
      for (int kk = 0; kk < 4; ++kk) {
        bf16x8 wf = *(const bf16x8*)(Wo + (db * 4 + kk) * 512 + lane * 8);
        acc[db][0] = MFMA(wf, at[0][kk], acc[db][0], 0, 0, 0);
        acc[db][1] = MFMA(wf, at[1][kk], acc[db][1], 0, 0, 0);
      }
  }

  // ---- residual + LN1 -> ybf (packed residual) + at2 (FFN B-frags) ----
  unsigned int ybf[2][8][2];
  bf16x8 at2[2][4];
#pragma unroll
  for (int tf = 0; tf < 2; ++tf) {
    const unsigned short* hrow = h + (tok0 + tf * 16 + c) * 128;
    float x[8][4];
    float s_ = 0.f, q_ = 0.f;
#pragma unroll
    for (int db = 0; db < 8; ++db) {
      float4 bvv = *(const float4*)(bo + db * 16 + g * 4);
      ushort4 rv = *(const ushort4*)(hrow + db * 16 + g * 4);
      x[db][0] = acc[db][tf][0] + bvv.x + bf2f(rv.x);
      x[db][1] = acc[db][tf][1] + bvv.y + bf2f(rv.y);
      x[db][2] = acc[db][tf][2] + bvv.z + bf2f(rv.z);
      x[db][3] = acc[db][tf][3] + bvv.w + bf2f(rv.w);
#pragma unroll
      for (int r = 0; r < 4; ++r) { s_ += x[db][r]; q_ += x[db][r] * x[db][r]; }
    }
    s_ += __shfl_xor(s_, 16); s_ += __shfl_xor(s_, 32);
    q_ += __shfl_xor(q_, 16); q_ += __shfl_xor(q_, 32);
    float mean = s_ * 0.0078125f;
    float var = q_ * 0.0078125f - mean * mean;
    float rs = rsqrtf(var + 1e-5f);
    f32x4 yv[8];
#pragma unroll
    for (int db = 0; db < 8; ++db) {
      float4 gv = *(const float4*)(g1 + db * 16 + g * 4);
      float4 bb = *(const float4*)(b1n + db * 16 + g * 4);
      yv[db][0] = (x[db][0] - mean) * rs * gv.x + bb.x;
      yv[db][1] = (x[db][1] - mean) * rs * gv.y + bb.y;
      yv[db][2] = (x[db][2] - mean) * rs * gv.z + bb.z;
      yv[db][3] = (x[db][3] - mean) * rs * gv.w + bb.w;
      ybf[tf][db][0] = cvtpk_bf16(yv[db][0], yv[db][1]);
      ybf[tf][db][1] = cvtpk_bf16(yv[db][2], yv[db][3]);
    }
#pragma unroll
    for (int kb = 0; kb < 4; ++kb)
      at2[tf][kb] = packfrag(yv[2 * kb], yv[2 * kb + 1]);
  }

  // ---- FFN (G register-resident) ----
  f32x4 acc2[8][2] = {};
  for (int s = 0; s < 16; ++s) {
    f32x4 d1[2][2] = {};
#pragma unroll
    for (int kk = 0; kk < 4; ++kk) {
      bf16x8 wa = *(const bf16x8*)(W1p + ((2 * s) * 4 + kk) * 512 + lane * 8);
      bf16x8 wb = *(const bf16x8*)(W1p + ((2 * s + 1) * 4 + kk) * 512 + lane * 8);
      d1[0][0] = MFMA(wa, at2[0][kk], d1[0][0], 0, 0, 0);
      d1[0][1] = MFMA(wa, at2[1][kk], d1[0][1], 0, 0, 0);
      d1[1][0] = MFMA(wb, at2[0][kk], d1[1][0], 0, 0, 0);
      d1[1][1] = MFMA(wb, at2[1][kk], d1[1][1], 0, 0, 0);
    }
    float4 bva = *(const float4*)(b1 + s * 32 + g * 4);
    float4 bvb = *(const float4*)(b1 + s * 32 + 16 + g * 4);
    bf16x8 gp[2];
#pragma unroll
    for (int tf = 0; tf < 2; ++tf) {
      f32x4 pa, pb;
      pa[0] = fmaxf(d1[0][tf][0] + bva.x, 0.f);
      pa[1] = fmaxf(d1[0][tf][1] + bva.y, 0.f);
      pa[2] = fmaxf(d1[0][tf][2] + bva.z, 0.f);
      pa[3] = fmaxf(d1[0][tf][3] + bva.w, 0.f);
      pb[0] = fmaxf(d1[1][tf][0] + bvb.x, 0.f);
      pb[1] = fmaxf(d1[1][tf][1] + bvb.y, 0.f);
      pb[2] = fmaxf(d1[1][tf][2] + bvb.z, 0.f);
      pb[3] = fmaxf(d1[1][tf][3] + bvb.w, 0.f);
      gp[tf] = packfrag(pa, pb);
    }
#pragma unroll
    for (int db = 0; db < 8; ++db) {
      bf16x8 w2 = *(const bf16x8*)(W2p + (db * 16 + s) * 512 + lane * 8);
      acc2[db][0] = MFMA(w2, gp[0], acc2[db][0], 0, 0, 0);
      acc2[db][1] = MFMA(w2, gp[1], acc2[db][1], 0, 0, 0);
    }
  }

  // ---- residual (ybf) + LN2 -> h ----
#pragma unroll
  for (int tf = 0; tf < 2; ++tf) {
    unsigned short* hrow = h + (tok0 + tf * 16 + c) * 128;
    float x[8][4];
    float s_ = 0.f, q_ = 0.f;
#pragma unroll
    for (int db = 0; db < 8; ++db) {
      float4 bvv = *(const float4*)(b2 + db * 16 + g * 4);
      unsigned int y01 = ybf[tf][db][0], y23 = ybf[tf][db][1];
      x[db][0] = acc2[db][tf][0] + bvv.x + bf2f((unsigned short)y01);
      x[db][1] = acc2[db][tf][1] + bvv.y + bf2f((unsigned short)(y01 >> 16));
      x[db][2] = acc2[db][tf][2] + bvv.z + bf2f((unsigned short)y23);
      x[db][3] = acc2[db][tf][3] + bvv.w + bf2f((unsigned short)(y23 >> 16));
#pragma unroll
      for (int r = 0; r < 4; ++r) { s_ += x[db][r]; q_ += x[db][r] * x[db][r]; }
    }
    s_ += __shfl_xor(s_, 16); s_ += __shfl_xor(s_, 32);
    q_ += __shfl_xor(q_, 16); q_ += __shfl_xor(q_, 32);
    float mean = s_ * 0.0078125f;
    float var = q_ * 0.0078125f - mean * mean;
    float rs = rsqrtf(var + 1e-5f);
#pragma unroll
    for (int db = 0; db < 8; ++db) {
      float4 gv = *(const float4*)(g2 + db * 16 + g * 4);
      float4 bb = *(const float4*)(b2n + db * 16 + g * 4);
      ushort4 o;
      o.x = f2bf((x[db][0] - mean) * rs * gv.x + bb.x);
      o.y = f2bf((x[db][1] - mean) * rs * gv.y + bb.y);
      o.z = f2bf((x[db][2] - mean) * rs * gv.z + bb.z);
      o.w = f2bf((x[db][3] - mean) * rs * gv.w + bb.w);
      *(ushort4*)(hrow + db * 16 + g * 4) = o;
    }
  }
}

// ---------------------------------------------------------------------------
// Fused vocab projection + entropy, register-transposed, no LDS/barriers.
// ---------------------------------------------------------------------------
__global__ __launch_bounds__(256) void vocab_entropy(
    const unsigned short* __restrict__ h, const unsigned short* __restrict__ Wp,
    const float* __restrict__ bias, float* __restrict__ ent) {
  const int lane = threadIdx.x & 63, w = threadIdx.x >> 6;
  const int c = lane & 15, g = lane >> 4;
  const size_t tok0 = (size_t)blockIdx.x * 128 + w * 32;

  bf16x8 at[2][4];
#pragma unroll
  for (int tf = 0; tf < 2; ++tf)
#pragma unroll
    for (int kk = 0; kk < 4; ++kk)
      at[tf][kk] =
          *(const bf16x8*)(h + (tok0 + tf * 16 + c) * 128 + kk * 32 + g * 8);

  f32x4 acc[16][2] = {};
#pragma unroll
  for (int vb = 0; vb < 16; ++vb)
#pragma unroll
    for (int kk = 0; kk < 4; ++kk) {
      bf16x8 wf = *(const bf16x8*)(Wp + (vb * 4 + kk) * 512 + lane * 8);
      acc[vb][0] = MFMA(wf, at[0][kk], acc[vb][0], 0, 0, 0);
      acc[vb][1] = MFMA(wf, at[1][kk], acc[vb][1], 0, 0, 0);
    }

  const float L2E = 1.4426950408889634f;
#pragma unroll
  for (int tf = 0; tf < 2; ++tf) {
    float m_ = -1e30f;
#pragma unroll
    for (int vb = 0; vb < 16; ++vb) {
      float4 bvv = *(const float4*)(bias + vb * 16 + g * 4);
      acc[vb][tf][0] += bvv.x; acc[vb][tf][1] += bvv.y;
      acc[vb][tf][2] += bvv.z; acc[vb][tf][3] += bvv.w;
      m_ = fmaxf(m_, fmaxf(fmaxf(acc[vb][tf][0], acc[vb][tf][1]),
                           fmaxf(acc[vb][tf][2], acc[vb][tf][3])));
    }
    m_ = fmaxf(m_, __shfl_xor(m_, 16));
    m_ = fmaxf(m_, __shfl_xor(m_, 32));
    float z_ = 0.f, sx_ = 0.f;
#pragma unroll
    for (int vb = 0; vb < 16; ++vb)
#pragma unroll
      for (int r = 0; r < 4; ++r) {
        float xx = acc[vb][tf][r];
        float e = EXP2((xx - m_) * L2E);
        z_ += e; sx_ += e * xx;
      }
    z_ += __shfl_xor(z_, 16);  z_ += __shfl_xor(z_, 32);
    sx_ += __shfl_xor(sx_, 16); sx_ += __shfl_xor(sx_, 32);
    if (g == 0) ent[tok0 + tf * 16 + c] = m_ + logf(z_) - sx_ / z_;
  }
}

// ---------------------------------------------------------------------------
__global__ __launch_bounds__(64) void avg_entropy_kernel(
    const float* __restrict__ ent, float* __restrict__ out) {
  int s = blockIdx.x, lane = threadIdx.x;
  float a = 0.f;
  for (int b = lane; b < 256; b += 64) a += ent[(size_t)b * 512 + s];
#pragma unroll
  for (int off = 32; off; off >>= 1) a += __shfl_xor(a, off);
  if (lane == 0) out[s] = a * 0.00390625f;
}

__global__ __launch_bounds__(512) void seg_kernel(float* out) {
  __shared__ int cs[512];
  int i = threadIdx.x;
  float e = out[i];
  cs[i] = (i >= 1 && e > 4.0f) ? 1 : 0;
  __syncthreads();
  for (int off = 1; off < 512; off <<= 1) {
    int v = (i >= off) ? cs[i - off] : 0;
    __syncthreads();
    cs[i] += v;
    __syncthreads();
  }
  out[512 + i] = (float)cs[i];
}

// ---------------------------------------------------------------------------
extern "C" void kernel_launch(void* const* d_in, const int* in_sizes, int n_in,
                              void* d_out, int out_size, void* d_ws,
                              size_t ws_size, hipStream_t stream) {
  (void)in_sizes; (void)n_in; (void)out_size; (void)ws_size;
  const int*   input_bytes = (const int*)d_in[0];
  const float* emb    = (const float*)d_in[1];
  const float* pos    = (const float*)d_in[2];
  const float* ln_g   = (const float*)d_in[3];
  const float* ln_b   = (const float*)d_in[4];
  const float* attn_w = (const float*)d_in[5];
  const float* attn_b = (const float*)d_in[6];
  const float* out_w  = (const float*)d_in[7];
  const float* out_b  = (const float*)d_in[8];
  const float* ff1_w  = (const float*)d_in[9];
  const float* ff1_b  = (const float*)d_in[10];
  const float* ff2_w  = (const float*)d_in[11];
  const float* ff2_b  = (const float*)d_in[12];
  const float* n1_g   = (const float*)d_in[13];
  const float* n1_b   = (const float*)d_in[14];
  const float* n2_g   = (const float*)d_in[15];
  const float* n2_b   = (const float*)d_in[16];
  const float* proj_w = (const float*)d_in[17];
  const float* proj_b = (const float*)d_in[18];

  char* ws = (char*)d_ws;
  unsigned short* hbf  = (unsigned short*)(ws);                // 32 MB
  unsigned short* obf  = (unsigned short*)(ws + 33554432);     // 32 MB
  unsigned short* wbf  = (unsigned short*)(ws + 67108864);     // ~0.85 MB
  float*          absb = (float*)(ws + 68157440);              // 3 KB
  float*          entb = (float*)(ws + 68161536);              // 0.5 MB

  unsigned short* attnA = wbf;
  unsigned short* outwA = wbf + 98304;
  unsigned short* w1A   = wbf + 131072;
  unsigned short* w2A   = wbf + 262144;
  unsigned short* projA = wbf + 393216;

  conv_attn_headA<<<384, 256, 0, stream>>>(attn_w, attnA);
  conv_attn_b<<<3, 256, 0, stream>>>(attn_b, absb);
  for (int l = 0; l < 2; ++l) {
    conv_permA<<<64, 256, 0, stream>>>(out_w + l * 16384, outwA + l * 16384,
                                       128, 16384);
    conv_permA<<<256, 256, 0, stream>>>(ff1_w + l * 65536, w1A + l * 65536,
                                        128, 65536);
    conv_permA<<<256, 256, 0, stream>>>(ff2_w + l * 65536, w2A + l * 65536,
                                        512, 65536);
  }
  conv_permA<<<128, 256, 0, stream>>>(proj_w, projA, 128, 32768);

  embed_ln<<<32768, 256, 0, stream>>>(input_bytes, emb, pos, ln_g, ln_b, hbf);

  for (int l = 0; l < 2; ++l) {
    attn_fused<<<1024, 512, 0, stream>>>(hbf, attnA + l * 49152,
                                         absb + l * 384, obf);
    block_tail<<<1024, 256, 0, stream>>>(
        obf, outwA + l * 16384, out_b + l * 128, n1_g + l * 128,
        n1_b + l * 128, w1A + l * 65536, ff1_b + l * 512, w2A + l * 65536,
        ff2_b + l * 128, n2_g + l * 128, n2_b + l * 128, hbf);
  }

  vocab_entropy<<<1024, 256, 0, stream>>>(hbf, projA, proj_b, entb);
  avg_entropy_kernel<<<512, 64, 0, stream>>>(entb, (float*)d_out);
  seg_kernel<<<1, 512, 0, stream>>>((float*)d_out);
}

// Round 13
// 456.575 us; speedup vs baseline: 1.1236x; 1.1236x over previous
//
#include <hip/hip_runtime.h>

// ---------------------------------------------------------------------------
// EntropyCalculator: 2-layer post-norm transformer encoder + entropy head.
// B=256 S=512 D=128 H=4 HD=32 FF=512 V=256
// Fused QKV+attention (setprio); register-transposed oproj/FFN/entropy.
// (round-11 structure; block_tail mega-fusion reverted — spilled)
// ---------------------------------------------------------------------------

typedef __bf16 bf16x8 __attribute__((ext_vector_type(8)));
typedef float  f32x4  __attribute__((ext_vector_type(4)));

__device__ __forceinline__ unsigned short f2bf(float f) {
  union { float f; unsigned int u; } c; c.f = f;
  unsigned int u = c.u;
  u += 0x7FFFu + ((u >> 16) & 1u);   // round-to-nearest-even
  return (unsigned short)(u >> 16);
}
__device__ __forceinline__ float bf2f(unsigned short u) {
  union { unsigned int u; float f; } c; c.u = ((unsigned int)u) << 16;
  return c.f;
}

__device__ __forceinline__ float EXP2(float x) {
#if __has_builtin(__builtin_amdgcn_exp2f)
  return __builtin_amdgcn_exp2f(x);
#else
  return exp2f(x);
#endif
}

__device__ __forceinline__ unsigned int cvtpk_bf16(float lo, float hi) {
  unsigned int r;
  asm("v_cvt_pk_bf16_f32 %0, %1, %2" : "=v"(r) : "v"(lo), "v"(hi));
  return r;
}
__device__ __forceinline__ void plswap32(unsigned int& a, unsigned int& b) {
  asm("v_permlane32_swap_b32 %0, %1" : "+v"(a), "+v"(b));
}
__device__ __forceinline__ void plswap16(unsigned int& a, unsigned int& b) {
  asm("v_permlane16_swap_b32 %0, %1" : "+v"(a), "+v"(b));
}
// Merge two mfma outputs (rows 0..15 / 16..31 on g*4+reg, col on c) into an
// operand frag: lane(c,g) = M[idx=c][32-dim packed g*8..g*8+7].
__device__ __forceinline__ bf16x8 packfrag(f32x4 a, f32x4 b) {
  unsigned int w00 = cvtpk_bf16(a[0], a[1]), w01 = cvtpk_bf16(a[2], a[3]);
  unsigned int w10 = cvtpk_bf16(b[0], b[1]), w11 = cvtpk_bf16(b[2], b[3]);
  plswap32(w00, w10); plswap16(w00, w10);
  plswap32(w01, w11); plswap16(w01, w11);
  union { unsigned int u[4]; bf16x8 v; } pk;
  pk.u[0] = w00; pk.u[1] = w01; pk.u[2] = w10; pk.u[3] = w11;
  return pk.v;
}

#define MFMA __builtin_amdgcn_mfma_f32_16x16x32_bf16

// ---------------------------------------------------------------------------
// weight conversions
// ---------------------------------------------------------------------------
__global__ void conv_permA(const float* __restrict__ src,
                           unsigned short* __restrict__ dst, int K, int n) {
  int i = blockIdx.x * 256 + threadIdx.x;
  if (i >= n) return;
  int row = i / K, k = i - row * K;
  int frag = (row >> 4) * (K >> 5) + (k >> 5);
  int d = frag * 512 + ((k >> 3) & 3) * 128 + (row & 15) * 8 + (k & 7);
  dst[d] = f2bf(src[i]);
}

// attn_w [2][384][128] -> per (layer, head, mat q/k/v) A-frag arrays of
// 2 db x 4 kk frags (4096 hw each).  Q rows pre-scaled.
#define QSCALE 0.2550602989892646f
__global__ void conv_attn_headA(const float* __restrict__ src,
                                unsigned short* __restrict__ dst) {
  int i = blockIdx.x * 256 + threadIdx.x;  // 98304
  int l = i / 49152, rem = i - l * 49152;
  int row = rem >> 7, k = rem & 127;
  int mat = row >> 7;            // 0=q 1=k 2=v
  int head = (row >> 5) & 3;
  int dr = row & 31;
  float v = src[i];
  if (mat == 0) v *= QSCALE;
  int d = ((l * 4 + head) * 3 + mat) * 4096 +
          ((dr >> 4) * 4 + (k >> 5)) * 512 + ((k >> 3) & 3) * 128 +
          (dr & 15) * 8 + (k & 7);
  dst[d] = f2bf(v);
}
__global__ void conv_attn_b(const float* __restrict__ src,
                            float* __restrict__ dst) {
  int i = blockIdx.x * 256 + threadIdx.x;  // 768
  if (i < 768) {
    float v = src[i];
    if ((i % 384) < 128) v *= QSCALE;
    dst[i] = v;
  }
}

// ---------------------------------------------------------------------------
// Embedding + LayerNorm -> bf16 residual stream.  One wave per token.
// ---------------------------------------------------------------------------
__global__ __launch_bounds__(256) void embed_ln(
    const int* __restrict__ bytes, const float* __restrict__ emb,
    const float* __restrict__ pos, const float* __restrict__ g,
    const float* __restrict__ bta, unsigned short* __restrict__ hbf) {
  int wv = threadIdx.x >> 6, lane = threadIdx.x & 63;
  int tok = blockIdx.x * 4 + wv;
  int s = tok & 511;
  int bidx = bytes[tok];
  const float* e = emb + (size_t)bidx * 128;
  const float* p = pos + (size_t)s * 128;
  float x0 = e[lane] + p[lane];
  float x1 = e[lane + 64] + p[lane + 64];
  float sum = x0 + x1, ssq = x0 * x0 + x1 * x1;
#pragma unroll
  for (int off = 32; off; off >>= 1) {
    sum += __shfl_xor(sum, off);
    ssq += __shfl_xor(ssq, off);
  }
  float mean = sum * 0.0078125f;
  float var = ssq * 0.0078125f - mean * mean;
  float rs = rsqrtf(var + 1e-5f);
  float y0 = (x0 - mean) * rs * g[lane] + bta[lane];
  float y1 = (x1 - mean) * rs * g[lane + 64] + bta[lane + 64];
  size_t o = (size_t)tok * 128;
  hbf[o + lane] = f2bf(y0); hbf[o + lane + 64] = f2bf(y1);
}

// ---------------------------------------------------------------------------
// Fused QKV + flash attention (+ s_setprio on MFMA clusters).
// One block (512 thr = 8 waves) per (b, head).
// ---------------------------------------------------------------------------
__global__ __launch_bounds__(512)
__attribute__((amdgpu_waves_per_eu(4, 4))) void attn_fused(
    const unsigned short* __restrict__ h, const unsigned short* __restrict__ Wa,
    const float* __restrict__ ab, unsigned short* __restrict__ obf) {
  __shared__ __bf16 Ks[32 * 512];
  __shared__ __bf16 Vt[32 * 512];

  const int hh = blockIdx.x & 3, bl = blockIdx.x >> 2;
  const int t = threadIdx.x;
  const int lane = t & 63, wv = t >> 6;
  const int c = lane & 15, g = lane >> 4;
  const size_t tok0 = (size_t)bl * 512;
  const size_t myq = tok0 + wv * 64;

  const unsigned short* Wb = Wa + hh * 3 * 4096;
  const float* bq = ab + hh * 32;
  const float* bk = ab + 128 + hh * 32;
  const float* bv = ab + 256 + hh * 32;

  bf16x8 qb[4];
  f32x4 dv[2][2];
#pragma unroll
  for (int tf = 0; tf < 4; ++tf) {
    bf16x8 a4[4];
#pragma unroll
    for (int kk = 0; kk < 4; ++kk)
      a4[kk] =
          *(const bf16x8*)(h + (myq + tf * 16 + c) * 128 + kk * 32 + g * 8);
    // ---- Q ----
    {
      f32x4 d0 = {}, d1 = {};
#pragma unroll
      for (int kk = 0; kk < 4; ++kk) {
        d0 = MFMA(*(const bf16x8*)(Wb + kk * 512 + lane * 8), a4[kk], d0,
                  0, 0, 0);
        d1 = MFMA(*(const bf16x8*)(Wb + (4 + kk) * 512 + lane * 8), a4[kk],
                  d1, 0, 0, 0);
      }
      float4 b0 = *(const float4*)(bq + g * 4);
      float4 b1 = *(const float4*)(bq + 16 + g * 4);
      d0[0] += b0.x; d0[1] += b0.y; d0[2] += b0.z; d0[3] += b0.w;
      d1[0] += b1.x; d1[1] += b1.y; d1[2] += b1.z; d1[3] += b1.w;
      qb[tf] = packfrag(d0, d1);
    }
    // ---- K ----
    {
      f32x4 d0 = {}, d1 = {};
#pragma unroll
      for (int kk = 0; kk < 4; ++kk) {
        d0 = MFMA(*(const bf16x8*)(Wb + 4096 + kk * 512 + lane * 8), a4[kk],
                  d0, 0, 0, 0);
        d1 = MFMA(*(const bf16x8*)(Wb + 4096 + (4 + kk) * 512 + lane * 8),
                  a4[kk], d1, 0, 0, 0);
      }
      float4 b0 = *(const float4*)(bk + g * 4);
      float4 b1 = *(const float4*)(bk + 16 + g * 4);
      d0[0] += b0.x; d0[1] += b0.y; d0[2] += b0.z; d0[3] += b0.w;
      d1[0] += b1.x; d1[1] += b1.y; d1[2] += b1.z; d1[3] += b1.w;
      *(bf16x8*)&Ks[(wv * 4 + tf) * 512 + lane * 8] = packfrag(d0, d1);
    }
    // ---- V ----
#pragma unroll
    for (int hf = 0; hf < 2; ++hf) {
      f32x4 tv = {};
#pragma unroll
      for (int kk = 0; kk < 4; ++kk)
        tv = MFMA(a4[kk],
                  *(const bf16x8*)(Wb + 8192 + (hf * 4 + kk) * 512 + lane * 8),
                  tv, 0, 0, 0);
      float bvv = bv[hf * 16 + c];
      tv[0] += bvv; tv[1] += bvv; tv[2] += bvv; tv[3] += bvv;
      dv[tf & 1][hf] = tv;
    }
    if (tf & 1) {
#pragma unroll
      for (int hf = 0; hf < 2; ++hf)
        *(bf16x8*)&Vt[(hf * 16 + wv * 2 + (tf >> 1)) * 512 + lane * 8] =
            packfrag(dv[0][hf], dv[1][hf]);
    }
  }
  __syncthreads();

  f32x4 ot[4][2] = {};
  float l[4] = {0.f, 0.f, 0.f, 0.f};
  const f32x4 zz = {0.f, 0.f, 0.f, 0.f};

  for (int kt = 0; kt < 8; ++kt) {
    bf16x8 ka[4];
#pragma unroll
    for (int kf = 0; kf < 4; ++kf)
      ka[kf] = *(const bf16x8*)&Ks[(kt * 4 + kf) * 512 + lane * 8];
    bf16x8 vb2[2][2];
#pragma unroll
    for (int hf = 0; hf < 2; ++hf)
#pragma unroll
      for (int ksl = 0; ksl < 2; ++ksl)
        vb2[hf][ksl] =
            *(const bf16x8*)&Vt[(hf * 16 + kt * 2 + ksl) * 512 + lane * 8];

#pragma unroll
    for (int qf = 0; qf < 4; ++qf) {
      __builtin_amdgcn_s_setprio(1);
      f32x4 sA = MFMA(ka[0], qb[qf], zz, 0, 0, 0);
      f32x4 sB = MFMA(ka[1], qb[qf], zz, 0, 0, 0);
      f32x4 sC = MFMA(ka[2], qb[qf], zz, 0, 0, 0);
      f32x4 sD = MFMA(ka[3], qb[qf], zz, 0, 0, 0);
      __builtin_amdgcn_s_setprio(0);

      {
        float pa0 = EXP2(sA[0]), pa1 = EXP2(sA[1]);
        float pa2 = EXP2(sA[2]), pa3 = EXP2(sA[3]);
        float pb0 = EXP2(sB[0]), pb1 = EXP2(sB[1]);
        float pb2 = EXP2(sB[2]), pb3 = EXP2(sB[3]);
        l[qf] += ((pa0 + pa1) + (pa2 + pa3)) + ((pb0 + pb1) + (pb2 + pb3));
        f32x4 pa = {pa0, pa1, pa2, pa3};
        f32x4 pb = {pb0, pb1, pb2, pb3};
        bf16x8 pk = packfrag(pa, pb);
        __builtin_amdgcn_s_setprio(1);
        ot[qf][0] = MFMA(vb2[0][0], pk, ot[qf][0], 0, 0, 0);
        ot[qf][1] = MFMA(vb2[1][0], pk, ot[qf][1], 0, 0, 0);
        __builtin_amdgcn_s_setprio(0);
      }
      {
        float pa0 = EXP2(sC[0]), pa1 = EXP2(sC[1]);
        float pa2 = EXP2(sC[2]), pa3 = EXP2(sC[3]);
        float pb0 = EXP2(sD[0]), pb1 = EXP2(sD[1]);
        float pb2 = EXP2(sD[2]), pb3 = EXP2(sD[3]);
        l[qf] += ((pa0 + pa1) + (pa2 + pa3)) + ((pb0 + pb1) + (pb2 + pb3));
        f32x4 pa = {pa0, pa1, pa2, pa3};
        f32x4 pb = {pb0, pb1, pb2, pb3};
        bf16x8 pk = packfrag(pa, pb);
        __builtin_amdgcn_s_setprio(1);
        ot[qf][0] = MFMA(vb2[0][1], pk, ot[qf][0], 0, 0, 0);
        ot[qf][1] = MFMA(vb2[1][1], pk, ot[qf][1], 0, 0, 0);
        __builtin_amdgcn_s_setprio(0);
      }
    }
  }

#pragma unroll
  for (int qf = 0; qf < 4; ++qf) {
    l[qf] += __shfl_xor(l[qf], 16);
    l[qf] += __shfl_xor(l[qf], 32);
  }
#pragma unroll
  for (int qf = 0; qf < 4; ++qf) {
    float rl = 1.0f / l[qf];
#pragma unroll
    for (int hf = 0; hf < 2; ++hf) {
      ushort4 pk;
      pk.x = f2bf(ot[qf][hf][0] * rl);
      pk.y = f2bf(ot[qf][hf][1] * rl);
      pk.z = f2bf(ot[qf][hf][2] * rl);
      pk.w = f2bf(ot[qf][hf][3] * rl);
      *(ushort4*)(obf + (myq + qf * 16 + c) * 128 + hh * 32 + hf * 16 +
                  g * 4) = pk;
    }
  }
}

// ---------------------------------------------------------------------------
// Fused out-proj + residual + LayerNorm, register-transposed, no LDS/barrier.
// ---------------------------------------------------------------------------
__global__ __launch_bounds__(256) void oproj_ln(
    const unsigned short* __restrict__ A, const unsigned short* __restrict__ Wp,
    const float* __restrict__ bias, unsigned short* __restrict__ h,
    const float* __restrict__ gamma, const float* __restrict__ beta) {
  const int lane = threadIdx.x & 63, w = threadIdx.x >> 6;
  const int c = lane & 15, g = lane >> 4;
  const size_t tok0 = (size_t)blockIdx.x * 128 + w * 32;

  bf16x8 at[2][4];
#pragma unroll
  for (int tf = 0; tf < 2; ++tf)
#pragma unroll
    for (int kk = 0; kk < 4; ++kk)
      at[tf][kk] =
          *(const bf16x8*)(A + (tok0 + tf * 16 + c) * 128 + kk * 32 + g * 8);

  f32x4 acc[8][2] = {};
#pragma unroll
  for (int db = 0; db < 8; ++db)
#pragma unroll
    for (int kk = 0; kk < 4; ++kk) {
      bf16x8 wf = *(const bf16x8*)(Wp + (db * 4 + kk) * 512 + lane * 8);
      acc[db][0] = MFMA(wf, at[0][kk], acc[db][0], 0, 0, 0);
      acc[db][1] = MFMA(wf, at[1][kk], acc[db][1], 0, 0, 0);
    }

#pragma unroll
  for (int tf = 0; tf < 2; ++tf) {
    unsigned short* hrow = h + (tok0 + tf * 16 + c) * 128;
    float x[8][4];
    float s_ = 0.f, q_ = 0.f;
#pragma unroll
    for (int db = 0; db < 8; ++db) {
      float4 bvv = *(const float4*)(bias + db * 16 + g * 4);
      ushort4 rv = *(const ushort4*)(hrow + db * 16 + g * 4);
      x[db][0] = acc[db][tf][0] + bvv.x + bf2f(rv.x);
      x[db][1] = acc[db][tf][1] + bvv.y + bf2f(rv.y);
      x[db][2] = acc[db][tf][2] + bvv.z + bf2f(rv.z);
      x[db][3] = acc[db][tf][3] + bvv.w + bf2f(rv.w);
#pragma unroll
      for (int r = 0; r < 4; ++r) { s_ += x[db][r]; q_ += x[db][r] * x[db][r]; }
    }
    s_ += __shfl_xor(s_, 16); s_ += __shfl_xor(s_, 32);
    q_ += __shfl_xor(q_, 16); q_ += __shfl_xor(q_, 32);
    float mean = s_ * 0.0078125f;
    float var = q_ * 0.0078125f - mean * mean;
    float rs = rsqrtf(var + 1e-5f);
#pragma unroll
    for (int db = 0; db < 8; ++db) {
      float4 gv = *(const float4*)(gamma + db * 16 + g * 4);
      float4 bb = *(const float4*)(beta + db * 16 + g * 4);
      ushort4 o;
      o.x = f2bf((x[db][0] - mean) * rs * gv.x + bb.x);
      o.y = f2bf((x[db][1] - mean) * rs * gv.y + bb.y);
      o.z = f2bf((x[db][2] - mean) * rs * gv.z + bb.z);
      o.w = f2bf((x[db][3] - mean) * rs * gv.w + bb.w);
      *(ushort4*)(hrow + db * 16 + g * 4) = o;
    }
  }
}

// ---------------------------------------------------------------------------
// Fused FFN, register-transposed, G never leaves registers, no LDS/barriers.
// waves_per_eu(3,4): 168-reg budget (static demand ~135) to avoid spill.
// ---------------------------------------------------------------------------
__global__ __launch_bounds__(256)
__attribute__((amdgpu_waves_per_eu(3, 4))) void ffn_reg(
    unsigned short* __restrict__ h, const unsigned short* __restrict__ W1p,
    const float* __restrict__ b1, const unsigned short* __restrict__ W2p,
    const float* __restrict__ b2, const float* __restrict__ gamma,
    const float* __restrict__ beta) {
  const int lane = threadIdx.x & 63, w = threadIdx.x >> 6;
  const int c = lane & 15, g = lane >> 4;
  const size_t tok0 = (size_t)blockIdx.x * 128 + w * 32;

  bf16x8 at[2][4];
#pragma unroll
  for (int tf = 0; tf < 2; ++tf)
#pragma unroll
    for (int kk = 0; kk < 4; ++kk)
      at[tf][kk] =
          *(const bf16x8*)(h + (tok0 + tf * 16 + c) * 128 + kk * 32 + g * 8);

  f32x4 acc[8][2] = {};
  for (int s = 0; s < 16; ++s) {          // 16 slices of 32 ff
    f32x4 d1[2][2] = {};                  // [ffhalf][tf]
#pragma unroll
    for (int kk = 0; kk < 4; ++kk) {
      bf16x8 wa = *(const bf16x8*)(W1p + ((2 * s) * 4 + kk) * 512 + lane * 8);
      bf16x8 wb = *(const bf16x8*)(W1p + ((2 * s + 1) * 4 + kk) * 512 + lane * 8);
      d1[0][0] = MFMA(wa, at[0][kk], d1[0][0], 0, 0, 0);
      d1[0][1] = MFMA(wa, at[1][kk], d1[0][1], 0, 0, 0);
      d1[1][0] = MFMA(wb, at[0][kk], d1[1][0], 0, 0, 0);
      d1[1][1] = MFMA(wb, at[1][kk], d1[1][1], 0, 0, 0);
    }
    float4 bva = *(const float4*)(b1 + s * 32 + g * 4);
    float4 bvb = *(const float4*)(b1 + s * 32 + 16 + g * 4);
    bf16x8 gp[2];
#pragma unroll
    for (int tf = 0; tf < 2; ++tf) {
      f32x4 pa, pb;
      pa[0] = fmaxf(d1[0][tf][0] + bva.x, 0.f);
      pa[1] = fmaxf(d1[0][tf][1] + bva.y, 0.f);
      pa[2] = fmaxf(d1[0][tf][2] + bva.z, 0.f);
      pa[3] = fmaxf(d1[0][tf][3] + bva.w, 0.f);
      pb[0] = fmaxf(d1[1][tf][0] + bvb.x, 0.f);
      pb[1] = fmaxf(d1[1][tf][1] + bvb.y, 0.f);
      pb[2] = fmaxf(d1[1][tf][2] + bvb.z, 0.f);
      pb[3] = fmaxf(d1[1][tf][3] + bvb.w, 0.f);
      gp[tf] = packfrag(pa, pb);
    }
#pragma unroll
    for (int db = 0; db < 8; ++db) {
      bf16x8 w2 = *(const bf16x8*)(W2p + (db * 16 + s) * 512 + lane * 8);
      acc[db][0] = MFMA(w2, gp[0], acc[db][0], 0, 0, 0);
      acc[db][1] = MFMA(w2, gp[1], acc[db][1], 0, 0, 0);
    }
  }

#pragma unroll
  for (int tf = 0; tf < 2; ++tf) {
    unsigned short* hrow = h + (tok0 + tf * 16 + c) * 128;
    float x[8][4];
    float s_ = 0.f, q_ = 0.f;
#pragma unroll
    for (int db = 0; db < 8; ++db) {
      float4 bvv = *(const float4*)(b2 + db * 16 + g * 4);
      ushort4 rv = *(const ushort4*)(hrow + db * 16 + g * 4);
      x[db][0] = acc[db][tf][0] + bvv.x + bf2f(rv.x);
      x[db][1] = acc[db][tf][1] + bvv.y + bf2f(rv.y);
      x[db][2] = acc[db][tf][2] + bvv.z + bf2f(rv.z);
      x[db][3] = acc[db][tf][3] + bvv.w + bf2f(rv.w);
#pragma unroll
      for (int r = 0; r < 4; ++r) { s_ += x[db][r]; q_ += x[db][r] * x[db][r]; }
    }
    s_ += __shfl_xor(s_, 16); s_ += __shfl_xor(s_, 32);
    q_ += __shfl_xor(q_, 16); q_ += __shfl_xor(q_, 32);
    float mean = s_ * 0.0078125f;
    float var = q_ * 0.0078125f - mean * mean;
    float rs = rsqrtf(var + 1e-5f);
#pragma unroll
    for (int db = 0; db < 8; ++db) {
      float4 gv = *(const float4*)(gamma + db * 16 + g * 4);
      float4 bb = *(const float4*)(beta + db * 16 + g * 4);
      ushort4 o;
      o.x = f2bf((x[db][0] - mean) * rs * gv.x + bb.x);
      o.y = f2bf((x[db][1] - mean) * rs * gv.y + bb.y);
      o.z = f2bf((x[db][2] - mean) * rs * gv.z + bb.z);
      o.w = f2bf((x[db][3] - mean) * rs * gv.w + bb.w);
      *(ushort4*)(hrow + db * 16 + g * 4) = o;
    }
  }
}

// ---------------------------------------------------------------------------
// Fused vocab projection + entropy, register-transposed, no LDS/barriers.
// ---------------------------------------------------------------------------
__global__ __launch_bounds__(256) void vocab_entropy(
    const unsigned short* __restrict__ h, const unsigned short* __restrict__ Wp,
    const float* __restrict__ bias, float* __restrict__ ent) {
  const int lane = threadIdx.x & 63, w = threadIdx.x >> 6;
  const int c = lane & 15, g = lane >> 4;
  const size_t tok0 = (size_t)blockIdx.x * 128 + w * 32;

  bf16x8 at[2][4];
#pragma unroll
  for (int tf = 0; tf < 2; ++tf)
#pragma unroll
    for (int kk = 0; kk < 4; ++kk)
      at[tf][kk] =
          *(const bf16x8*)(h + (tok0 + tf * 16 + c) * 128 + kk * 32 + g * 8);

  f32x4 acc[16][2] = {};
#pragma unroll
  for (int vb = 0; vb < 16; ++vb)
#pragma unroll
    for (int kk = 0; kk < 4; ++kk) {
      bf16x8 wf = *(const bf16x8*)(Wp + (vb * 4 + kk) * 512 + lane * 8);
      acc[vb][0] = MFMA(wf, at[0][kk], acc[vb][0], 0, 0, 0);
      acc[vb][1] = MFMA(wf, at[1][kk], acc[vb][1], 0, 0, 0);
    }

  const float L2E = 1.4426950408889634f;
#pragma unroll
  for (int tf = 0; tf < 2; ++tf) {
    float m_ = -1e30f;
#pragma unroll
    for (int vb = 0; vb < 16; ++vb) {
      float4 bvv = *(const float4*)(bias + vb * 16 + g * 4);
      acc[vb][tf][0] += bvv.x; acc[vb][tf][1] += bvv.y;
      acc[vb][tf][2] += bvv.z; acc[vb][tf][3] += bvv.w;
      m_ = fmaxf(m_, fmaxf(fmaxf(acc[vb][tf][0], acc[vb][tf][1]),
                           fmaxf(acc[vb][tf][2], acc[vb][tf][3])));
    }
    m_ = fmaxf(m_, __shfl_xor(m_, 16));
    m_ = fmaxf(m_, __shfl_xor(m_, 32));
    float z_ = 0.f, sx_ = 0.f;
#pragma unroll
    for (int vb = 0; vb < 16; ++vb)
#pragma unroll
      for (int r = 0; r < 4; ++r) {
        float xx = acc[vb][tf][r];
        float e = EXP2((xx - m_) * L2E);
        z_ += e; sx_ += e * xx;
      }
    z_ += __shfl_xor(z_, 16);  z_ += __shfl_xor(z_, 32);
    sx_ += __shfl_xor(sx_, 16); sx_ += __shfl_xor(sx_, 32);
    if (g == 0) ent[tok0 + tf * 16 + c] = m_ + logf(z_) - sx_ / z_;
  }
}

// ---------------------------------------------------------------------------
__global__ __launch_bounds__(64) void avg_entropy_kernel(
    const float* __restrict__ ent, float* __restrict__ out) {
  int s = blockIdx.x, lane = threadIdx.x;
  float a = 0.f;
  for (int b = lane; b < 256; b += 64) a += ent[(size_t)b * 512 + s];
#pragma unroll
  for (int off = 32; off; off >>= 1) a += __shfl_xor(a, off);
  if (lane == 0) out[s] = a * 0.00390625f;
}

__global__ __launch_bounds__(512) void seg_kernel(float* out) {
  __shared__ int cs[512];
  int i = threadIdx.x;
  float e = out[i];
  cs[i] = (i >= 1 && e > 4.0f) ? 1 : 0;
  __syncthreads();
  for (int off = 1; off < 512; off <<= 1) {
    int v = (i >= off) ? cs[i - off] : 0;
    __syncthreads();
    cs[i] += v;
    __syncthreads();
  }
  out[512 + i] = (float)cs[i];
}

// ---------------------------------------------------------------------------
extern "C" void kernel_launch(void* const* d_in, const int* in_sizes, int n_in,
                              void* d_out, int out_size, void* d_ws,
                              size_t ws_size, hipStream_t stream) {
  (void)in_sizes; (void)n_in; (void)out_size; (void)ws_size;
  const int*   input_bytes = (const int*)d_in[0];
  const float* emb    = (const float*)d_in[1];
  const float* pos    = (const float*)d_in[2];
  const float* ln_g   = (const float*)d_in[3];
  const float* ln_b   = (const float*)d_in[4];
  const float* attn_w = (const float*)d_in[5];
  const float* attn_b = (const float*)d_in[6];
  const float* out_w  = (const float*)d_in[7];
  const float* out_b  = (const float*)d_in[8];
  const float* ff1_w  = (const float*)d_in[9];
  const float* ff1_b  = (const float*)d_in[10];
  const float* ff2_w  = (const float*)d_in[11];
  const float* ff2_b  = (const float*)d_in[12];
  const float* n1_g   = (const float*)d_in[13];
  const float* n1_b   = (const float*)d_in[14];
  const float* n2_g   = (const float*)d_in[15];
  const float* n2_b   = (const float*)d_in[16];
  const float* proj_w = (const float*)d_in[17];
  const float* proj_b = (const float*)d_in[18];

  char* ws = (char*)d_ws;
  unsigned short* hbf  = (unsigned short*)(ws);                // 32 MB
  unsigned short* obf  = (unsigned short*)(ws + 33554432);     // 32 MB
  unsigned short* wbf  = (unsigned short*)(ws + 67108864);     // ~0.85 MB
  float*          absb = (float*)(ws + 68157440);              // 3 KB
  float*          entb = (float*)(ws + 68161536);              // 0.5 MB

  unsigned short* attnA = wbf;
  unsigned short* outwA = wbf + 98304;
  unsigned short* w1A   = wbf + 131072;
  unsigned short* w2A   = wbf + 262144;
  unsigned short* projA = wbf + 393216;

  conv_attn_headA<<<384, 256, 0, stream>>>(attn_w, attnA);
  conv_attn_b<<<3, 256, 0, stream>>>(attn_b, absb);
  for (int l = 0; l < 2; ++l) {
    conv_permA<<<64, 256, 0, stream>>>(out_w + l * 16384, outwA + l * 16384,
                                       128, 16384);
    conv_permA<<<256, 256, 0, stream>>>(ff1_w + l * 65536, w1A + l * 65536,
                                        128, 65536);
    conv_permA<<<256, 256, 0, stream>>>(ff2_w + l * 65536, w2A + l * 65536,
                                        512, 65536);
  }
  conv_permA<<<128, 256, 0, stream>>>(proj_w, projA, 128, 32768);

  embed_ln<<<32768, 256, 0, stream>>>(input_bytes, emb, pos, ln_g, ln_b, hbf);

  for (int l = 0; l < 2; ++l) {
    attn_fused<<<1024, 512, 0, stream>>>(hbf, attnA + l * 49152,
                                         absb + l * 384, obf);
    oproj_ln<<<1024, 256, 0, stream>>>(obf, outwA + l * 16384, out_b + l * 128,
                                       hbf, n1_g + l * 128, n1_b + l * 128);
    ffn_reg<<<1024, 256, 0, stream>>>(hbf, w1A + l * 65536, ff1_b + l * 512,
                                      w2A + l * 65536, ff2_b + l * 128,
                                      n2_g + l * 128, n2_b + l * 128);
  }

  vocab_entropy<<<1024, 256, 0, stream>>>(hbf, projA, proj_b, entb);
  avg_entropy_kernel<<<512, 64, 0, stream>>>(entb, (float*)d_out);
  seg_kernel<<<1, 512, 0, stream>>>((float*)d_out);
}

// Round 14
// 413.293 us; speedup vs baseline: 1.2413x; 1.1047x over previous
//
#include <hip/hip_runtime.h>

// ---------------------------------------------------------------------------
// EntropyCalculator: 2-layer post-norm transformer encoder + entropy head.
// B=256 S=512 D=128 H=4 HD=32 FF=512 V=256
// Fused QKV+attention (setprio); register-transposed oproj/FFN/entropy.
// (ffn_reg waves_per_eu pin reverted — it induced spill; attn setprio kept)
// ---------------------------------------------------------------------------

typedef __bf16 bf16x8 __attribute__((ext_vector_type(8)));
typedef float  f32x4  __attribute__((ext_vector_type(4)));

__device__ __forceinline__ unsigned short f2bf(float f) {
  union { float f; unsigned int u; } c; c.f = f;
  unsigned int u = c.u;
  u += 0x7FFFu + ((u >> 16) & 1u);   // round-to-nearest-even
  return (unsigned short)(u >> 16);
}
__device__ __forceinline__ float bf2f(unsigned short u) {
  union { unsigned int u; float f; } c; c.u = ((unsigned int)u) << 16;
  return c.f;
}

__device__ __forceinline__ float EXP2(float x) {
#if __has_builtin(__builtin_amdgcn_exp2f)
  return __builtin_amdgcn_exp2f(x);
#else
  return exp2f(x);
#endif
}

__device__ __forceinline__ unsigned int cvtpk_bf16(float lo, float hi) {
  unsigned int r;
  asm("v_cvt_pk_bf16_f32 %0, %1, %2" : "=v"(r) : "v"(lo), "v"(hi));
  return r;
}
__device__ __forceinline__ void plswap32(unsigned int& a, unsigned int& b) {
  asm("v_permlane32_swap_b32 %0, %1" : "+v"(a), "+v"(b));
}
__device__ __forceinline__ void plswap16(unsigned int& a, unsigned int& b) {
  asm("v_permlane16_swap_b32 %0, %1" : "+v"(a), "+v"(b));
}
// Merge two mfma outputs (rows 0..15 / 16..31 on g*4+reg, col on c) into an
// operand frag: lane(c,g) = M[idx=c][32-dim packed g*8..g*8+7].
__device__ __forceinline__ bf16x8 packfrag(f32x4 a, f32x4 b) {
  unsigned int w00 = cvtpk_bf16(a[0], a[1]), w01 = cvtpk_bf16(a[2], a[3]);
  unsigned int w10 = cvtpk_bf16(b[0], b[1]), w11 = cvtpk_bf16(b[2], b[3]);
  plswap32(w00, w10); plswap16(w00, w10);
  plswap32(w01, w11); plswap16(w01, w11);
  union { unsigned int u[4]; bf16x8 v; } pk;
  pk.u[0] = w00; pk.u[1] = w01; pk.u[2] = w10; pk.u[3] = w11;
  return pk.v;
}

#define MFMA __builtin_amdgcn_mfma_f32_16x16x32_bf16

// ---------------------------------------------------------------------------
// weight conversions
// ---------------------------------------------------------------------------
__global__ void conv_permA(const float* __restrict__ src,
                           unsigned short* __restrict__ dst, int K, int n) {
  int i = blockIdx.x * 256 + threadIdx.x;
  if (i >= n) return;
  int row = i / K, k = i - row * K;
  int frag = (row >> 4) * (K >> 5) + (k >> 5);
  int d = frag * 512 + ((k >> 3) & 3) * 128 + (row & 15) * 8 + (k & 7);
  dst[d] = f2bf(src[i]);
}

// attn_w [2][384][128] -> per (layer, head, mat q/k/v) A-frag arrays of
// 2 db x 4 kk frags (4096 hw each).  Q rows pre-scaled.
#define QSCALE 0.2550602989892646f
__global__ void conv_attn_headA(const float* __restrict__ src,
                                unsigned short* __restrict__ dst) {
  int i = blockIdx.x * 256 + threadIdx.x;  // 98304
  int l = i / 49152, rem = i - l * 49152;
  int row = rem >> 7, k = rem & 127;
  int mat = row >> 7;            // 0=q 1=k 2=v
  int head = (row >> 5) & 3;
  int dr = row & 31;
  float v = src[i];
  if (mat == 0) v *= QSCALE;
  int d = ((l * 4 + head) * 3 + mat) * 4096 +
          ((dr >> 4) * 4 + (k >> 5)) * 512 + ((k >> 3) & 3) * 128 +
          (dr & 15) * 8 + (k & 7);
  dst[d] = f2bf(v);
}
__global__ void conv_attn_b(const float* __restrict__ src,
                            float* __restrict__ dst) {
  int i = blockIdx.x * 256 + threadIdx.x;  // 768
  if (i < 768) {
    float v = src[i];
    if ((i % 384) < 128) v *= QSCALE;
    dst[i] = v;
  }
}

// ---------------------------------------------------------------------------
// Embedding + LayerNorm -> bf16 residual stream.  One wave per token.
// ---------------------------------------------------------------------------
__global__ __launch_bounds__(256) void embed_ln(
    const int* __restrict__ bytes, const float* __restrict__ emb,
    const float* __restrict__ pos, const float* __restrict__ g,
    const float* __restrict__ bta, unsigned short* __restrict__ hbf) {
  int wv = threadIdx.x >> 6, lane = threadIdx.x & 63;
  int tok = blockIdx.x * 4 + wv;
  int s = tok & 511;
  int bidx = bytes[tok];
  const float* e = emb + (size_t)bidx * 128;
  const float* p = pos + (size_t)s * 128;
  float x0 = e[lane] + p[lane];
  float x1 = e[lane + 64] + p[lane + 64];
  float sum = x0 + x1, ssq = x0 * x0 + x1 * x1;
#pragma unroll
  for (int off = 32; off; off >>= 1) {
    sum += __shfl_xor(sum, off);
    ssq += __shfl_xor(ssq, off);
  }
  float mean = sum * 0.0078125f;
  float var = ssq * 0.0078125f - mean * mean;
  float rs = rsqrtf(var + 1e-5f);
  float y0 = (x0 - mean) * rs * g[lane] + bta[lane];
  float y1 = (x1 - mean) * rs * g[lane + 64] + bta[lane + 64];
  size_t o = (size_t)tok * 128;
  hbf[o + lane] = f2bf(y0); hbf[o + lane + 64] = f2bf(y1);
}

// ---------------------------------------------------------------------------
// Fused QKV + flash attention (+ s_setprio on MFMA clusters).
// One block (512 thr = 8 waves) per (b, head).
// ---------------------------------------------------------------------------
__global__ __launch_bounds__(512)
__attribute__((amdgpu_waves_per_eu(4, 4))) void attn_fused(
    const unsigned short* __restrict__ h, const unsigned short* __restrict__ Wa,
    const float* __restrict__ ab, unsigned short* __restrict__ obf) {
  __shared__ __bf16 Ks[32 * 512];
  __shared__ __bf16 Vt[32 * 512];

  const int hh = blockIdx.x & 3, bl = blockIdx.x >> 2;
  const int t = threadIdx.x;
  const int lane = t & 63, wv = t >> 6;
  const int c = lane & 15, g = lane >> 4;
  const size_t tok0 = (size_t)bl * 512;
  const size_t myq = tok0 + wv * 64;

  const unsigned short* Wb = Wa + hh * 3 * 4096;
  const float* bq = ab + hh * 32;
  const float* bk = ab + 128 + hh * 32;
  const float* bv = ab + 256 + hh * 32;

  bf16x8 qb[4];
  f32x4 dv[2][2];
#pragma unroll
  for (int tf = 0; tf < 4; ++tf) {
    bf16x8 a4[4];
#pragma unroll
    for (int kk = 0; kk < 4; ++kk)
      a4[kk] =
          *(const bf16x8*)(h + (myq + tf * 16 + c) * 128 + kk * 32 + g * 8);
    // ---- Q ----
    {
      f32x4 d0 = {}, d1 = {};
#pragma unroll
      for (int kk = 0; kk < 4; ++kk) {
        d0 = MFMA(*(const bf16x8*)(Wb + kk * 512 + lane * 8), a4[kk], d0,
                  0, 0, 0);
        d1 = MFMA(*(const bf16x8*)(Wb + (4 + kk) * 512 + lane * 8), a4[kk],
                  d1, 0, 0, 0);
      }
      float4 b0 = *(const float4*)(bq + g * 4);
      float4 b1 = *(const float4*)(bq + 16 + g * 4);
      d0[0] += b0.x; d0[1] += b0.y; d0[2] += b0.z; d0[3] += b0.w;
      d1[0] += b1.x; d1[1] += b1.y; d1[2] += b1.z; d1[3] += b1.w;
      qb[tf] = packfrag(d0, d1);
    }
    // ---- K ----
    {
      f32x4 d0 = {}, d1 = {};
#pragma unroll
      for (int kk = 0; kk < 4; ++kk) {
        d0 = MFMA(*(const bf16x8*)(Wb + 4096 + kk * 512 + lane * 8), a4[kk],
                  d0, 0, 0, 0);
        d1 = MFMA(*(const bf16x8*)(Wb + 4096 + (4 + kk) * 512 + lane * 8),
                  a4[kk], d1, 0, 0, 0);
      }
      float4 b0 = *(const float4*)(bk + g * 4);
      float4 b1 = *(const float4*)(bk + 16 + g * 4);
      d0[0] += b0.x; d0[1] += b0.y; d0[2] += b0.z; d0[3] += b0.w;
      d1[0] += b1.x; d1[1] += b1.y; d1[2] += b1.z; d1[3] += b1.w;
      *(bf16x8*)&Ks[(wv * 4 + tf) * 512 + lane * 8] = packfrag(d0, d1);
    }
    // ---- V ----
#pragma unroll
    for (int hf = 0; hf < 2; ++hf) {
      f32x4 tv = {};
#pragma unroll
      for (int kk = 0; kk < 4; ++kk)
        tv = MFMA(a4[kk],
                  *(const bf16x8*)(Wb + 8192 + (hf * 4 + kk) * 512 + lane * 8),
                  tv, 0, 0, 0);
      float bvv = bv[hf * 16 + c];
      tv[0] += bvv; tv[1] += bvv; tv[2] += bvv; tv[3] += bvv;
      dv[tf & 1][hf] = tv;
    }
    if (tf & 1) {
#pragma unroll
      for (int hf = 0; hf < 2; ++hf)
        *(bf16x8*)&Vt[(hf * 16 + wv * 2 + (tf >> 1)) * 512 + lane * 8] =
            packfrag(dv[0][hf], dv[1][hf]);
    }
  }
  __syncthreads();

  f32x4 ot[4][2] = {};
  float l[4] = {0.f, 0.f, 0.f, 0.f};
  const f32x4 zz = {0.f, 0.f, 0.f, 0.f};

  for (int kt = 0; kt < 8; ++kt) {
    bf16x8 ka[4];
#pragma unroll
    for (int kf = 0; kf < 4; ++kf)
      ka[kf] = *(const bf16x8*)&Ks[(kt * 4 + kf) * 512 + lane * 8];
    bf16x8 vb2[2][2];
#pragma unroll
    for (int hf = 0; hf < 2; ++hf)
#pragma unroll
      for (int ksl = 0; ksl < 2; ++ksl)
        vb2[hf][ksl] =
            *(const bf16x8*)&Vt[(hf * 16 + kt * 2 + ksl) * 512 + lane * 8];

#pragma unroll
    for (int qf = 0; qf < 4; ++qf) {
      __builtin_amdgcn_s_setprio(1);
      f32x4 sA = MFMA(ka[0], qb[qf], zz, 0, 0, 0);
      f32x4 sB = MFMA(ka[1], qb[qf], zz, 0, 0, 0);
      f32x4 sC = MFMA(ka[2], qb[qf], zz, 0, 0, 0);
      f32x4 sD = MFMA(ka[3], qb[qf], zz, 0, 0, 0);
      __builtin_amdgcn_s_setprio(0);

      {
        float pa0 = EXP2(sA[0]), pa1 = EXP2(sA[1]);
        float pa2 = EXP2(sA[2]), pa3 = EXP2(sA[3]);
        float pb0 = EXP2(sB[0]), pb1 = EXP2(sB[1]);
        float pb2 = EXP2(sB[2]), pb3 = EXP2(sB[3]);
        l[qf] += ((pa0 + pa1) + (pa2 + pa3)) + ((pb0 + pb1) + (pb2 + pb3));
        f32x4 pa = {pa0, pa1, pa2, pa3};
        f32x4 pb = {pb0, pb1, pb2, pb3};
        bf16x8 pk = packfrag(pa, pb);
        __builtin_amdgcn_s_setprio(1);
        ot[qf][0] = MFMA(vb2[0][0], pk, ot[qf][0], 0, 0, 0);
        ot[qf][1] = MFMA(vb2[1][0], pk, ot[qf][1], 0, 0, 0);
        __builtin_amdgcn_s_setprio(0);
      }
      {
        float pa0 = EXP2(sC[0]), pa1 = EXP2(sC[1]);
        float pa2 = EXP2(sC[2]), pa3 = EXP2(sC[3]);
        float pb0 = EXP2(sD[0]), pb1 = EXP2(sD[1]);
        float pb2 = EXP2(sD[2]), pb3 = EXP2(sD[3]);
        l[qf] += ((pa0 + pa1) + (pa2 + pa3)) + ((pb0 + pb1) + (pb2 + pb3));
        f32x4 pa = {pa0, pa1, pa2, pa3};
        f32x4 pb = {pb0, pb1, pb2, pb3};
        bf16x8 pk = packfrag(pa, pb);
        __builtin_amdgcn_s_setprio(1);
        ot[qf][0] = MFMA(vb2[0][1], pk, ot[qf][0], 0, 0, 0);
        ot[qf][1] = MFMA(vb2[1][1], pk, ot[qf][1], 0, 0, 0);
        __builtin_amdgcn_s_setprio(0);
      }
    }
  }

#pragma unroll
  for (int qf = 0; qf < 4; ++qf) {
    l[qf] += __shfl_xor(l[qf], 16);
    l[qf] += __shfl_xor(l[qf], 32);
  }
#pragma unroll
  for (int qf = 0; qf < 4; ++qf) {
    float rl = 1.0f / l[qf];
#pragma unroll
    for (int hf = 0; hf < 2; ++hf) {
      ushort4 pk;
      pk.x = f2bf(ot[qf][hf][0] * rl);
      pk.y = f2bf(ot[qf][hf][1] * rl);
      pk.z = f2bf(ot[qf][hf][2] * rl);
      pk.w = f2bf(ot[qf][hf][3] * rl);
      *(ushort4*)(obf + (myq + qf * 16 + c) * 128 + hh * 32 + hf * 16 +
                  g * 4) = pk;
    }
  }
}

// ---------------------------------------------------------------------------
// Fused out-proj + residual + LayerNorm, register-transposed, no LDS/barrier.
// ---------------------------------------------------------------------------
__global__ __launch_bounds__(256) void oproj_ln(
    const unsigned short* __restrict__ A, const unsigned short* __restrict__ Wp,
    const float* __restrict__ bias, unsigned short* __restrict__ h,
    const float* __restrict__ gamma, const float* __restrict__ beta) {
  const int lane = threadIdx.x & 63, w = threadIdx.x >> 6;
  const int c = lane & 15, g = lane >> 4;
  const size_t tok0 = (size_t)blockIdx.x * 128 + w * 32;

  bf16x8 at[2][4];
#pragma unroll
  for (int tf = 0; tf < 2; ++tf)
#pragma unroll
    for (int kk = 0; kk < 4; ++kk)
      at[tf][kk] =
          *(const bf16x8*)(A + (tok0 + tf * 16 + c) * 128 + kk * 32 + g * 8);

  f32x4 acc[8][2] = {};
#pragma unroll
  for (int db = 0; db < 8; ++db)
#pragma unroll
    for (int kk = 0; kk < 4; ++kk) {
      bf16x8 wf = *(const bf16x8*)(Wp + (db * 4 + kk) * 512 + lane * 8);
      acc[db][0] = MFMA(wf, at[0][kk], acc[db][0], 0, 0, 0);
      acc[db][1] = MFMA(wf, at[1][kk], acc[db][1], 0, 0, 0);
    }

#pragma unroll
  for (int tf = 0; tf < 2; ++tf) {
    unsigned short* hrow = h + (tok0 + tf * 16 + c) * 128;
    float x[8][4];
    float s_ = 0.f, q_ = 0.f;
#pragma unroll
    for (int db = 0; db < 8; ++db) {
      float4 bvv = *(const float4*)(bias + db * 16 + g * 4);
      ushort4 rv = *(const ushort4*)(hrow + db * 16 + g * 4);
      x[db][0] = acc[db][tf][0] + bvv.x + bf2f(rv.x);
      x[db][1] = acc[db][tf][1] + bvv.y + bf2f(rv.y);
      x[db][2] = acc[db][tf][2] + bvv.z + bf2f(rv.z);
      x[db][3] = acc[db][tf][3] + bvv.w + bf2f(rv.w);
#pragma unroll
      for (int r = 0; r < 4; ++r) { s_ += x[db][r]; q_ += x[db][r] * x[db][r]; }
    }
    s_ += __shfl_xor(s_, 16); s_ += __shfl_xor(s_, 32);
    q_ += __shfl_xor(q_, 16); q_ += __shfl_xor(q_, 32);
    float mean = s_ * 0.0078125f;
    float var = q_ * 0.0078125f - mean * mean;
    float rs = rsqrtf(var + 1e-5f);
#pragma unroll
    for (int db = 0; db < 8; ++db) {
      float4 gv = *(const float4*)(gamma + db * 16 + g * 4);
      float4 bb = *(const float4*)(beta + db * 16 + g * 4);
      ushort4 o;
      o.x = f2bf((x[db][0] - mean) * rs * gv.x + bb.x);
      o.y = f2bf((x[db][1] - mean) * rs * gv.y + bb.y);
      o.z = f2bf((x[db][2] - mean) * rs * gv.z + bb.z);
      o.w = f2bf((x[db][3] - mean) * rs * gv.w + bb.w);
      *(ushort4*)(hrow + db * 16 + g * 4) = o;
    }
  }
}

// ---------------------------------------------------------------------------
// Fused FFN, register-transposed, G never leaves registers, no LDS/barriers.
// ---------------------------------------------------------------------------
__global__ __launch_bounds__(256) void ffn_reg(
    unsigned short* __restrict__ h, const unsigned short* __restrict__ W1p,
    const float* __restrict__ b1, const unsigned short* __restrict__ W2p,
    const float* __restrict__ b2, const float* __restrict__ gamma,
    const float* __restrict__ beta) {
  const int lane = threadIdx.x & 63, w = threadIdx.x >> 6;
  const int c = lane & 15, g = lane >> 4;
  const size_t tok0 = (size_t)blockIdx.x * 128 + w * 32;

  bf16x8 at[2][4];
#pragma unroll
  for (int tf = 0; tf < 2; ++tf)
#pragma unroll
    for (int kk = 0; kk < 4; ++kk)
      at[tf][kk] =
          *(const bf16x8*)(h + (tok0 + tf * 16 + c) * 128 + kk * 32 + g * 8);

  f32x4 acc[8][2] = {};
  for (int s = 0; s < 16; ++s) {          // 16 slices of 32 ff
    f32x4 d1[2][2] = {};                  // [ffhalf][tf]
#pragma unroll
    for (int kk = 0; kk < 4; ++kk) {
      bf16x8 wa = *(const bf16x8*)(W1p + ((2 * s) * 4 + kk) * 512 + lane * 8);
      bf16x8 wb = *(const bf16x8*)(W1p + ((2 * s + 1) * 4 + kk) * 512 + lane * 8);
      d1[0][0] = MFMA(wa, at[0][kk], d1[0][0], 0, 0, 0);
      d1[0][1] = MFMA(wa, at[1][kk], d1[0][1], 0, 0, 0);
      d1[1][0] = MFMA(wb, at[0][kk], d1[1][0], 0, 0, 0);
      d1[1][1] = MFMA(wb, at[1][kk], d1[1][1], 0, 0, 0);
    }
    float4 bva = *(const float4*)(b1 + s * 32 + g * 4);
    float4 bvb = *(const float4*)(b1 + s * 32 + 16 + g * 4);
    bf16x8 gp[2];
#pragma unroll
    for (int tf = 0; tf < 2; ++tf) {
      f32x4 pa, pb;
      pa[0] = fmaxf(d1[0][tf][0] + bva.x, 0.f);
      pa[1] = fmaxf(d1[0][tf][1] + bva.y, 0.f);
      pa[2] = fmaxf(d1[0][tf][2] + bva.z, 0.f);
      pa[3] = fmaxf(d1[0][tf][3] + bva.w, 0.f);
      pb[0] = fmaxf(d1[1][tf][0] + bvb.x, 0.f);
      pb[1] = fmaxf(d1[1][tf][1] + bvb.y, 0.f);
      pb[2] = fmaxf(d1[1][tf][2] + bvb.z, 0.f);
      pb[3] = fmaxf(d1[1][tf][3] + bvb.w, 0.f);
      gp[tf] = packfrag(pa, pb);
    }
#pragma unroll
    for (int db = 0; db < 8; ++db) {
      bf16x8 w2 = *(const bf16x8*)(W2p + (db * 16 + s) * 512 + lane * 8);
      acc[db][0] = MFMA(w2, gp[0], acc[db][0], 0, 0, 0);
      acc[db][1] = MFMA(w2, gp[1], acc[db][1], 0, 0, 0);
    }
  }

#pragma unroll
  for (int tf = 0; tf < 2; ++tf) {
    unsigned short* hrow = h + (tok0 + tf * 16 + c) * 128;
    float x[8][4];
    float s_ = 0.f, q_ = 0.f;
#pragma unroll
    for (int db = 0; db < 8; ++db) {
      float4 bvv = *(const float4*)(b2 + db * 16 + g * 4);
      ushort4 rv = *(const ushort4*)(hrow + db * 16 + g * 4);
      x[db][0] = acc[db][tf][0] + bvv.x + bf2f(rv.x);
      x[db][1] = acc[db][tf][1] + bvv.y + bf2f(rv.y);
      x[db][2] = acc[db][tf][2] + bvv.z + bf2f(rv.z);
      x[db][3] = acc[db][tf][3] + bvv.w + bf2f(rv.w);
#pragma unroll
      for (int r = 0; r < 4; ++r) { s_ += x[db][r]; q_ += x[db][r] * x[db][r]; }
    }
    s_ += __shfl_xor(s_, 16); s_ += __shfl_xor(s_, 32);
    q_ += __shfl_xor(q_, 16); q_ += __shfl_xor(q_, 32);
    float mean = s_ * 0.0078125f;
    float var = q_ * 0.0078125f - mean * mean;
    float rs = rsqrtf(var + 1e-5f);
#pragma unroll
    for (int db = 0; db < 8; ++db) {
      float4 gv = *(const float4*)(gamma + db * 16 + g * 4);
      float4 bb = *(const float4*)(beta + db * 16 + g * 4);
      ushort4 o;
      o.x = f2bf((x[db][0] - mean) * rs * gv.x + bb.x);
      o.y = f2bf((x[db][1] - mean) * rs * gv.y + bb.y);
      o.z = f2bf((x[db][2] - mean) * rs * gv.z + bb.z);
      o.w = f2bf((x[db][3] - mean) * rs * gv.w + bb.w);
      *(ushort4*)(hrow + db * 16 + g * 4) = o;
    }
  }
}

// ---------------------------------------------------------------------------
// Fused vocab projection + entropy, register-transposed, no LDS/barriers.
// ---------------------------------------------------------------------------
__global__ __launch_bounds__(256) void vocab_entropy(
    const unsigned short* __restrict__ h, const unsigned short* __restrict__ Wp,
    const float* __restrict__ bias, float* __restrict__ ent) {
  const int lane = threadIdx.x & 63, w = threadIdx.x >> 6;
  const int c = lane & 15, g = lane >> 4;
  const size_t tok0 = (size_t)blockIdx.x * 128 + w * 32;

  bf16x8 at[2][4];
#pragma unroll
  for (int tf = 0; tf < 2; ++tf)
#pragma unroll
    for (int kk = 0; kk < 4; ++kk)
      at[tf][kk] =
          *(const bf16x8*)(h + (tok0 + tf * 16 + c) * 128 + kk * 32 + g * 8);

  f32x4 acc[16][2] = {};
#pragma unroll
  for (int vb = 0; vb < 16; ++vb)
#pragma unroll
    for (int kk = 0; kk < 4; ++kk) {
      bf16x8 wf = *(const bf16x8*)(Wp + (vb * 4 + kk) * 512 + lane * 8);
      acc[vb][0] = MFMA(wf, at[0][kk], acc[vb][0], 0, 0, 0);
      acc[vb][1] = MFMA(wf, at[1][kk], acc[vb][1], 0, 0, 0);
    }

  const float L2E = 1.4426950408889634f;
#pragma unroll
  for (int tf = 0; tf < 2; ++tf) {
    float m_ = -1e30f;
#pragma unroll
    for (int vb = 0; vb < 16; ++vb) {
      float4 bvv = *(const float4*)(bias + vb * 16 + g * 4);
      acc[vb][tf][0] += bvv.x; acc[vb][tf][1] += bvv.y;
      acc[vb][tf][2] += bvv.z; acc[vb][tf][3] += bvv.w;
      m_ = fmaxf(m_, fmaxf(fmaxf(acc[vb][tf][0], acc[vb][tf][1]),
                           fmaxf(acc[vb][tf][2], acc[vb][tf][3])));
    }
    m_ = fmaxf(m_, __shfl_xor(m_, 16));
    m_ = fmaxf(m_, __shfl_xor(m_, 32));
    float z_ = 0.f, sx_ = 0.f;
#pragma unroll
    for (int vb = 0; vb < 16; ++vb)
#pragma unroll
      for (int r = 0; r < 4; ++r) {
        float xx = acc[vb][tf][r];
        float e = EXP2((xx - m_) * L2E);
        z_ += e; sx_ += e * xx;
      }
    z_ += __shfl_xor(z_, 16);  z_ += __shfl_xor(z_, 32);
    sx_ += __shfl_xor(sx_, 16); sx_ += __shfl_xor(sx_, 32);
    if (g == 0) ent[tok0 + tf * 16 + c] = m_ + logf(z_) - sx_ / z_;
  }
}

// ---------------------------------------------------------------------------
__global__ __launch_bounds__(64) void avg_entropy_kernel(
    const float* __restrict__ ent, float* __restrict__ out) {
  int s = blockIdx.x, lane = threadIdx.x;
  float a = 0.f;
  for (int b = lane; b < 256; b += 64) a += ent[(size_t)b * 512 + s];
#pragma unroll
  for (int off = 32; off; off >>= 1) a += __shfl_xor(a, off);
  if (lane == 0) out[s] = a * 0.00390625f;
}

__global__ __launch_bounds__(512) void seg_kernel(float* out) {
  __shared__ int cs[512];
  int i = threadIdx.x;
  float e = out[i];
  cs[i] = (i >= 1 && e > 4.0f) ? 1 : 0;
  __syncthreads();
  for (int off = 1; off < 512; off <<= 1) {
    int v = (i >= off) ? cs[i - off] : 0;
    __syncthreads();
    cs[i] += v;
    __syncthreads();
  }
  out[512 + i] = (float)cs[i];
}

// ---------------------------------------------------------------------------
extern "C" void kernel_launch(void* const* d_in, const int* in_sizes, int n_in,
                              void* d_out, int out_size, void* d_ws,
                              size_t ws_size, hipStream_t stream) {
  (void)in_sizes; (void)n_in; (void)out_size; (void)ws_size;
  const int*   input_bytes = (const int*)d_in[0];
  const float* emb    = (const float*)d_in[1];
  const float* pos    = (const float*)d_in[2];
  const float* ln_g   = (const float*)d_in[3];
  const float* ln_b   = (const float*)d_in[4];
  const float* attn_w = (const float*)d_in[5];
  const float* attn_b = (const float*)d_in[6];
  const float* out_w  = (const float*)d_in[7];
  const float* out_b  = (const float*)d_in[8];
  const float* ff1_w  = (const float*)d_in[9];
  const float* ff1_b  = (const float*)d_in[10];
  const float* ff2_w  = (const float*)d_in[11];
  const float* ff2_b  = (const float*)d_in[12];
  const float* n1_g   = (const float*)d_in[13];
  const float* n1_b   = (const float*)d_in[14];
  const float* n2_g   = (const float*)d_in[15];
  const float* n2_b   = (const float*)d_in[16];
  const float* proj_w = (const float*)d_in[17];
  const float* proj_b = (const float*)d_in[18];

  char* ws = (char*)d_ws;
  unsigned short* hbf  = (unsigned short*)(ws);                // 32 MB
  unsigned short* obf  = (unsigned short*)(ws + 33554432);     // 32 MB
  unsigned short* wbf  = (unsigned short*)(ws + 67108864);     // ~0.85 MB
  float*          absb = (float*)(ws + 68157440);              // 3 KB
  float*          entb = (float*)(ws + 68161536);              // 0.5 MB

  unsigned short* attnA = wbf;
  unsigned short* outwA = wbf + 98304;
  unsigned short* w1A   = wbf + 131072;
  unsigned short* w2A   = wbf + 262144;
  unsigned short* projA = wbf + 393216;

  conv_attn_headA<<<384, 256, 0, stream>>>(attn_w, attnA);
  conv_attn_b<<<3, 256, 0, stream>>>(attn_b, absb);
  for (int l = 0; l < 2; ++l) {
    conv_permA<<<64, 256, 0, stream>>>(out_w + l * 16384, outwA + l * 16384,
                                       128, 16384);
    conv_permA<<<256, 256, 0, stream>>>(ff1_w + l * 65536, w1A + l * 65536,
                                        128, 65536);
    conv_permA<<<256, 256, 0, stream>>>(ff2_w + l * 65536, w2A + l * 65536,
                                        512, 65536);
  }
  conv_permA<<<128, 256, 0, stream>>>(proj_w, projA, 128, 32768);

  embed_ln<<<32768, 256, 0, stream>>>(input_bytes, emb, pos, ln_g, ln_b, hbf);

  for (int l = 0; l < 2; ++l) {
    attn_fused<<<1024, 512, 0, stream>>>(hbf, attnA + l * 49152,
                                         absb + l * 384, obf);
    oproj_ln<<<1024, 256, 0, stream>>>(obf, outwA + l * 16384, out_b + l * 128,
                                       hbf, n1_g + l * 128, n1_b + l * 128);
    ffn_reg<<<1024, 256, 0, stream>>>(hbf, w1A + l * 65536, ff1_b + l * 512,
                                      w2A + l * 65536, ff2_b + l * 128,
                                      n2_g + l * 128, n2_b + l * 128);
  }

  vocab_entropy<<<1024, 256, 0, stream>>>(hbf, projA, proj_b, entb);
  avg_entropy_kernel<<<512, 64, 0, stream>>>(entb, (float*)d_out);
  seg_kernel<<<1, 512, 0, stream>>>((float*)d_out);
}

// Round 15
// 405.620 us; speedup vs baseline: 1.2647x; 1.0189x over previous
//
#include <hip/hip_runtime.h>

// ---------------------------------------------------------------------------
// EntropyCalculator: 2-layer post-norm transformer encoder + entropy head.
// B=256 S=512 D=128 H=4 HD=32 FF=512 V=256
// Fused QKV+attention (setprio, ones-MFMA l, XCD swizzle);
// register-transposed oproj/FFN/entropy.
// ---------------------------------------------------------------------------

typedef __bf16 bf16x8 __attribute__((ext_vector_type(8)));
typedef float  f32x4  __attribute__((ext_vector_type(4)));

__device__ __forceinline__ unsigned short f2bf(float f) {
  union { float f; unsigned int u; } c; c.f = f;
  unsigned int u = c.u;
  u += 0x7FFFu + ((u >> 16) & 1u);   // round-to-nearest-even
  return (unsigned short)(u >> 16);
}
__device__ __forceinline__ float bf2f(unsigned short u) {
  union { unsigned int u; float f; } c; c.u = ((unsigned int)u) << 16;
  return c.f;
}

__device__ __forceinline__ float EXP2(float x) {
#if __has_builtin(__builtin_amdgcn_exp2f)
  return __builtin_amdgcn_exp2f(x);
#else
  return exp2f(x);
#endif
}

__device__ __forceinline__ unsigned int cvtpk_bf16(float lo, float hi) {
  unsigned int r;
  asm("v_cvt_pk_bf16_f32 %0, %1, %2" : "=v"(r) : "v"(lo), "v"(hi));
  return r;
}
__device__ __forceinline__ void plswap32(unsigned int& a, unsigned int& b) {
  asm("v_permlane32_swap_b32 %0, %1" : "+v"(a), "+v"(b));
}
__device__ __forceinline__ void plswap16(unsigned int& a, unsigned int& b) {
  asm("v_permlane16_swap_b32 %0, %1" : "+v"(a), "+v"(b));
}
// Merge two mfma outputs (rows 0..15 / 16..31 on g*4+reg, col on c) into an
// operand frag: lane(c,g) = M[idx=c][32-dim packed g*8..g*8+7].
__device__ __forceinline__ bf16x8 packfrag(f32x4 a, f32x4 b) {
  unsigned int w00 = cvtpk_bf16(a[0], a[1]), w01 = cvtpk_bf16(a[2], a[3]);
  unsigned int w10 = cvtpk_bf16(b[0], b[1]), w11 = cvtpk_bf16(b[2], b[3]);
  plswap32(w00, w10); plswap16(w00, w10);
  plswap32(w01, w11); plswap16(w01, w11);
  union { unsigned int u[4]; bf16x8 v; } pk;
  pk.u[0] = w00; pk.u[1] = w01; pk.u[2] = w10; pk.u[3] = w11;
  return pk.v;
}

#define MFMA __builtin_amdgcn_mfma_f32_16x16x32_bf16

// ---------------------------------------------------------------------------
// weight conversions
// ---------------------------------------------------------------------------
__global__ void conv_permA(const float* __restrict__ src,
                           unsigned short* __restrict__ dst, int K, int n) {
  int i = blockIdx.x * 256 + threadIdx.x;
  if (i >= n) return;
  int row = i / K, k = i - row * K;
  int frag = (row >> 4) * (K >> 5) + (k >> 5);
  int d = frag * 512 + ((k >> 3) & 3) * 128 + (row & 15) * 8 + (k & 7);
  dst[d] = f2bf(src[i]);
}

// attn_w [2][384][128] -> per (layer, head, mat q/k/v) A-frag arrays of
// 2 db x 4 kk frags (4096 hw each).  Q rows pre-scaled.
#define QSCALE 0.2550602989892646f
__global__ void conv_attn_headA(const float* __restrict__ src,
                                unsigned short* __restrict__ dst) {
  int i = blockIdx.x * 256 + threadIdx.x;  // 98304
  int l = i / 49152, rem = i - l * 49152;
  int row = rem >> 7, k = rem & 127;
  int mat = row >> 7;            // 0=q 1=k 2=v
  int head = (row >> 5) & 3;
  int dr = row & 31;
  float v = src[i];
  if (mat == 0) v *= QSCALE;
  int d = ((l * 4 + head) * 3 + mat) * 4096 +
          ((dr >> 4) * 4 + (k >> 5)) * 512 + ((k >> 3) & 3) * 128 +
          (dr & 15) * 8 + (k & 7);
  dst[d] = f2bf(v);
}
__global__ void conv_attn_b(const float* __restrict__ src,
                            float* __restrict__ dst) {
  int i = blockIdx.x * 256 + threadIdx.x;  // 768
  if (i < 768) {
    float v = src[i];
    if ((i % 384) < 128) v *= QSCALE;
    dst[i] = v;
  }
}

// ---------------------------------------------------------------------------
// Embedding + LayerNorm -> bf16 residual stream.  One wave per token.
// ---------------------------------------------------------------------------
__global__ __launch_bounds__(256) void embed_ln(
    const int* __restrict__ bytes, const float* __restrict__ emb,
    const float* __restrict__ pos, const float* __restrict__ g,
    const float* __restrict__ bta, unsigned short* __restrict__ hbf) {
  int wv = threadIdx.x >> 6, lane = threadIdx.x & 63;
  int tok = blockIdx.x * 4 + wv;
  int s = tok & 511;
  int bidx = bytes[tok];
  const float* e = emb + (size_t)bidx * 128;
  const float* p = pos + (size_t)s * 128;
  float x0 = e[lane] + p[lane];
  float x1 = e[lane + 64] + p[lane + 64];
  float sum = x0 + x1, ssq = x0 * x0 + x1 * x1;
#pragma unroll
  for (int off = 32; off; off >>= 1) {
    sum += __shfl_xor(sum, off);
    ssq += __shfl_xor(ssq, off);
  }
  float mean = sum * 0.0078125f;
  float var = ssq * 0.0078125f - mean * mean;
  float rs = rsqrtf(var + 1e-5f);
  float y0 = (x0 - mean) * rs * g[lane] + bta[lane];
  float y1 = (x1 - mean) * rs * g[lane + 64] + bta[lane + 64];
  size_t o = (size_t)tok * 128;
  hbf[o + lane] = f2bf(y0); hbf[o + lane + 64] = f2bf(y1);
}

// ---------------------------------------------------------------------------
// Fused QKV + flash attention.  s_setprio on MFMA clusters; softmax
// denominator via ones-MFMA (lane-local, no shfl); XCD-aware block swizzle
// (the 4 head-blocks of a batch share blockIdx%8 -> same XCD L2).
// One block (512 thr = 8 waves) per (b, head).
// ---------------------------------------------------------------------------
__global__ __launch_bounds__(512)
__attribute__((amdgpu_waves_per_eu(4, 4))) void attn_fused(
    const unsigned short* __restrict__ h, const unsigned short* __restrict__ Wa,
    const float* __restrict__ ab, unsigned short* __restrict__ obf) {
  __shared__ __bf16 Ks[32 * 512];
  __shared__ __bf16 Vt[32 * 512];

  // XCD swizzle: idx = b0 + 8*hh + 32*b1 ; bl = b0 + 8*b1
  const int idx = blockIdx.x;
  const int hh = (idx >> 3) & 3;
  const int bl = (idx & 7) + ((idx >> 5) << 3);
  const int t = threadIdx.x;
  const int lane = t & 63, wv = t >> 6;
  const int c = lane & 15, g = lane >> 4;
  const size_t tok0 = (size_t)bl * 512;
  const size_t myq = tok0 + wv * 64;

  const unsigned short* Wb = Wa + hh * 3 * 4096;
  const float* bq = ab + hh * 32;
  const float* bk = ab + 128 + hh * 32;
  const float* bv = ab + 256 + hh * 32;

  bf16x8 qb[4];
  f32x4 dv[2][2];
#pragma unroll
  for (int tf = 0; tf < 4; ++tf) {
    bf16x8 a4[4];
#pragma unroll
    for (int kk = 0; kk < 4; ++kk)
      a4[kk] =
          *(const bf16x8*)(h + (myq + tf * 16 + c) * 128 + kk * 32 + g * 8);
    // ---- Q ----
    {
      f32x4 d0 = {}, d1 = {};
#pragma unroll
      for (int kk = 0; kk < 4; ++kk) {
        d0 = MFMA(*(const bf16x8*)(Wb + kk * 512 + lane * 8), a4[kk], d0,
                  0, 0, 0);
        d1 = MFMA(*(const bf16x8*)(Wb + (4 + kk) * 512 + lane * 8), a4[kk],
                  d1, 0, 0, 0);
      }
      float4 b0 = *(const float4*)(bq + g * 4);
      float4 b1 = *(const float4*)(bq + 16 + g * 4);
      d0[0] += b0.x; d0[1] += b0.y; d0[2] += b0.z; d0[3] += b0.w;
      d1[0] += b1.x; d1[1] += b1.y; d1[2] += b1.z; d1[3] += b1.w;
      qb[tf] = packfrag(d0, d1);
    }
    // ---- K ----
    {
      f32x4 d0 = {}, d1 = {};
#pragma unroll
      for (int kk = 0; kk < 4; ++kk) {
        d0 = MFMA(*(const bf16x8*)(Wb + 4096 + kk * 512 + lane * 8), a4[kk],
                  d0, 0, 0, 0);
        d1 = MFMA(*(const bf16x8*)(Wb + 4096 + (4 + kk) * 512 + lane * 8),
                  a4[kk], d1, 0, 0, 0);
      }
      float4 b0 = *(const float4*)(bk + g * 4);
      float4 b1 = *(const float4*)(bk + 16 + g * 4);
      d0[0] += b0.x; d0[1] += b0.y; d0[2] += b0.z; d0[3] += b0.w;
      d1[0] += b1.x; d1[1] += b1.y; d1[2] += b1.z; d1[3] += b1.w;
      *(bf16x8*)&Ks[(wv * 4 + tf) * 512 + lane * 8] = packfrag(d0, d1);
    }
    // ---- V ----
#pragma unroll
    for (int hf = 0; hf < 2; ++hf) {
      f32x4 tv = {};
#pragma unroll
      for (int kk = 0; kk < 4; ++kk)
        tv = MFMA(a4[kk],
                  *(const bf16x8*)(Wb + 8192 + (hf * 4 + kk) * 512 + lane * 8),
                  tv, 0, 0, 0);
      float bvv = bv[hf * 16 + c];
      tv[0] += bvv; tv[1] += bvv; tv[2] += bvv; tv[3] += bvv;
      dv[tf & 1][hf] = tv;
    }
    if (tf & 1) {
#pragma unroll
      for (int hf = 0; hf < 2; ++hf)
        *(bf16x8*)&Vt[(hf * 16 + wv * 2 + (tf >> 1)) * 512 + lane * 8] =
            packfrag(dv[0][hf], dv[1][hf]);
    }
  }
  __syncthreads();

  // ones A-frag for l accumulation: out[r][c] = sum_k P^T[k][c] = l(query c)
  bf16x8 onesv;
#pragma unroll
  for (int i = 0; i < 8; ++i) onesv[i] = (__bf16)1.0f;

  f32x4 ot[4][2] = {};
  f32x4 lacc[4] = {};
  const f32x4 zz = {0.f, 0.f, 0.f, 0.f};

  for (int kt = 0; kt < 8; ++kt) {
    bf16x8 ka[4];
#pragma unroll
    for (int kf = 0; kf < 4; ++kf)
      ka[kf] = *(const bf16x8*)&Ks[(kt * 4 + kf) * 512 + lane * 8];
    bf16x8 vb2[2][2];
#pragma unroll
    for (int hf = 0; hf < 2; ++hf)
#pragma unroll
      for (int ksl = 0; ksl < 2; ++ksl)
        vb2[hf][ksl] =
            *(const bf16x8*)&Vt[(hf * 16 + kt * 2 + ksl) * 512 + lane * 8];

#pragma unroll
    for (int qf = 0; qf < 4; ++qf) {
      __builtin_amdgcn_s_setprio(1);
      f32x4 sA = MFMA(ka[0], qb[qf], zz, 0, 0, 0);
      f32x4 sB = MFMA(ka[1], qb[qf], zz, 0, 0, 0);
      f32x4 sC = MFMA(ka[2], qb[qf], zz, 0, 0, 0);
      f32x4 sD = MFMA(ka[3], qb[qf], zz, 0, 0, 0);
      __builtin_amdgcn_s_setprio(0);

      {
        float pa0 = EXP2(sA[0]), pa1 = EXP2(sA[1]);
        float pa2 = EXP2(sA[2]), pa3 = EXP2(sA[3]);
        float pb0 = EXP2(sB[0]), pb1 = EXP2(sB[1]);
        float pb2 = EXP2(sB[2]), pb3 = EXP2(sB[3]);
        f32x4 pa = {pa0, pa1, pa2, pa3};
        f32x4 pb = {pb0, pb1, pb2, pb3};
        bf16x8 pk = packfrag(pa, pb);
        __builtin_amdgcn_s_setprio(1);
        ot[qf][0] = MFMA(vb2[0][0], pk, ot[qf][0], 0, 0, 0);
        ot[qf][1] = MFMA(vb2[1][0], pk, ot[qf][1], 0, 0, 0);
        lacc[qf] = MFMA(onesv, pk, lacc[qf], 0, 0, 0);
        __builtin_amdgcn_s_setprio(0);
      }
      {
        float pa0 = EXP2(sC[0]), pa1 = EXP2(sC[1]);
        float pa2 = EXP2(sC[2]), pa3 = EXP2(sC[3]);
        float pb0 = EXP2(sD[0]), pb1 = EXP2(sD[1]);
        float pb2 = EXP2(sD[2]), pb3 = EXP2(sD[3]);
        f32x4 pa = {pa0, pa1, pa2, pa3};
        f32x4 pb = {pb0, pb1, pb2, pb3};
        bf16x8 pk = packfrag(pa, pb);
        __builtin_amdgcn_s_setprio(1);
        ot[qf][0] = MFMA(vb2[0][1], pk, ot[qf][0], 0, 0, 0);
        ot[qf][1] = MFMA(vb2[1][1], pk, ot[qf][1], 0, 0, 0);
        lacc[qf] = MFMA(onesv, pk, lacc[qf], 0, 0, 0);
        __builtin_amdgcn_s_setprio(0);
      }
    }
  }

#pragma unroll
  for (int qf = 0; qf < 4; ++qf) {
    float rl = 1.0f / lacc[qf][0];   // all 4 rows identical: l for query c
#pragma unroll
    for (int hf = 0; hf < 2; ++hf) {
      ushort4 pk;
      pk.x = f2bf(ot[qf][hf][0] * rl);
      pk.y = f2bf(ot[qf][hf][1] * rl);
      pk.z = f2bf(ot[qf][hf][2] * rl);
      pk.w = f2bf(ot[qf][hf][3] * rl);
      *(ushort4*)(obf + (myq + qf * 16 + c) * 128 + hh * 32 + hf * 16 +
                  g * 4) = pk;
    }
  }
}

// ---------------------------------------------------------------------------
// Fused out-proj + residual + LayerNorm, register-transposed, no LDS/barrier.
// ---------------------------------------------------------------------------
__global__ __launch_bounds__(256) void oproj_ln(
    const unsigned short* __restrict__ A, const unsigned short* __restrict__ Wp,
    const float* __restrict__ bias, unsigned short* __restrict__ h,
    const float* __restrict__ gamma, const float* __restrict__ beta) {
  const int lane = threadIdx.x & 63, w = threadIdx.x >> 6;
  const int c = lane & 15, g = lane >> 4;
  const size_t tok0 = (size_t)blockIdx.x * 128 + w * 32;

  bf16x8 at[2][4];
#pragma unroll
  for (int tf = 0; tf < 2; ++tf)
#pragma unroll
    for (int kk = 0; kk < 4; ++kk)
      at[tf][kk] =
          *(const bf16x8*)(A + (tok0 + tf * 16 + c) * 128 + kk * 32 + g * 8);

  f32x4 acc[8][2] = {};
#pragma unroll
  for (int db = 0; db < 8; ++db)
#pragma unroll
    for (int kk = 0; kk < 4; ++kk) {
      bf16x8 wf = *(const bf16x8*)(Wp + (db * 4 + kk) * 512 + lane * 8);
      acc[db][0] = MFMA(wf, at[0][kk], acc[db][0], 0, 0, 0);
      acc[db][1] = MFMA(wf, at[1][kk], acc[db][1], 0, 0, 0);
    }

#pragma unroll
  for (int tf = 0; tf < 2; ++tf) {
    unsigned short* hrow = h + (tok0 + tf * 16 + c) * 128;
    float x[8][4];
    float s_ = 0.f, q_ = 0.f;
#pragma unroll
    for (int db = 0; db < 8; ++db) {
      float4 bvv = *(const float4*)(bias + db * 16 + g * 4);
      ushort4 rv = *(const ushort4*)(hrow + db * 16 + g * 4);
      x[db][0] = acc[db][tf][0] + bvv.x + bf2f(rv.x);
      x[db][1] = acc[db][tf][1] + bvv.y + bf2f(rv.y);
      x[db][2] = acc[db][tf][2] + bvv.z + bf2f(rv.z);
      x[db][3] = acc[db][tf][3] + bvv.w + bf2f(rv.w);
#pragma unroll
      for (int r = 0; r < 4; ++r) { s_ += x[db][r]; q_ += x[db][r] * x[db][r]; }
    }
    s_ += __shfl_xor(s_, 16); s_ += __shfl_xor(s_, 32);
    q_ += __shfl_xor(q_, 16); q_ += __shfl_xor(q_, 32);
    float mean = s_ * 0.0078125f;
    float var = q_ * 0.0078125f - mean * mean;
    float rs = rsqrtf(var + 1e-5f);
#pragma unroll
    for (int db = 0; db < 8; ++db) {
      float4 gv = *(const float4*)(gamma + db * 16 + g * 4);
      float4 bb = *(const float4*)(beta + db * 16 + g * 4);
      ushort4 o;
      o.x = f2bf((x[db][0] - mean) * rs * gv.x + bb.x);
      o.y = f2bf((x[db][1] - mean) * rs * gv.y + bb.y);
      o.z = f2bf((x[db][2] - mean) * rs * gv.z + bb.z);
      o.w = f2bf((x[db][3] - mean) * rs * gv.w + bb.w);
      *(ushort4*)(hrow + db * 16 + g * 4) = o;
    }
  }
}

// ---------------------------------------------------------------------------
// Fused FFN, register-transposed, G never leaves registers, no LDS/barriers.
// ---------------------------------------------------------------------------
__global__ __launch_bounds__(256) void ffn_reg(
    unsigned short* __restrict__ h, const unsigned short* __restrict__ W1p,
    const float* __restrict__ b1, const unsigned short* __restrict__ W2p,
    const float* __restrict__ b2, const float* __restrict__ gamma,
    const float* __restrict__ beta) {
  const int lane = threadIdx.x & 63, w = threadIdx.x >> 6;
  const int c = lane & 15, g = lane >> 4;
  const size_t tok0 = (size_t)blockIdx.x * 128 + w * 32;

  bf16x8 at[2][4];
#pragma unroll
  for (int tf = 0; tf < 2; ++tf)
#pragma unroll
    for (int kk = 0; kk < 4; ++kk)
      at[tf][kk] =
          *(const bf16x8*)(h + (tok0 + tf * 16 + c) * 128 + kk * 32 + g * 8);

  f32x4 acc[8][2] = {};
  for (int s = 0; s < 16; ++s) {          // 16 slices of 32 ff
    f32x4 d1[2][2] = {};                  // [ffhalf][tf]
#pragma unroll
    for (int kk = 0; kk < 4; ++kk) {
      bf16x8 wa = *(const bf16x8*)(W1p + ((2 * s) * 4 + kk) * 512 + lane * 8);
      bf16x8 wb = *(const bf16x8*)(W1p + ((2 * s + 1) * 4 + kk) * 512 + lane * 8);
      d1[0][0] = MFMA(wa, at[0][kk], d1[0][0], 0, 0, 0);
      d1[0][1] = MFMA(wa, at[1][kk], d1[0][1], 0, 0, 0);
      d1[1][0] = MFMA(wb, at[0][kk], d1[1][0], 0, 0, 0);
      d1[1][1] = MFMA(wb, at[1][kk], d1[1][1], 0, 0, 0);
    }
    float4 bva = *(const float4*)(b1 + s * 32 + g * 4);
    float4 bvb = *(const float4*)(b1 + s * 32 + 16 + g * 4);
    bf16x8 gp[2];
#pragma unroll
    for (int tf = 0; tf < 2; ++tf) {
      f32x4 pa, pb;
      pa[0] = fmaxf(d1[0][tf][0] + bva.x, 0.f);
      pa[1] = fmaxf(d1[0][tf][1] + bva.y, 0.f);
      pa[2] = fmaxf(d1[0][tf][2] + bva.z, 0.f);
      pa[3] = fmaxf(d1[0][tf][3] + bva.w, 0.f);
      pb[0] = fmaxf(d1[1][tf][0] + bvb.x, 0.f);
      pb[1] = fmaxf(d1[1][tf][1] + bvb.y, 0.f);
      pb[2] = fmaxf(d1[1][tf][2] + bvb.z, 0.f);
      pb[3] = fmaxf(d1[1][tf][3] + bvb.w, 0.f);
      gp[tf] = packfrag(pa, pb);
    }
#pragma unroll
    for (int db = 0; db < 8; ++db) {
      bf16x8 w2 = *(const bf16x8*)(W2p + (db * 16 + s) * 512 + lane * 8);
      acc[db][0] = MFMA(w2, gp[0], acc[db][0], 0, 0, 0);
      acc[db][1] = MFMA(w2, gp[1], acc[db][1], 0, 0, 0);
    }
  }

#pragma unroll
  for (int tf = 0; tf < 2; ++tf) {
    unsigned short* hrow = h + (tok0 + tf * 16 + c) * 128;
    float x[8][4];
    float s_ = 0.f, q_ = 0.f;
#pragma unroll
    for (int db = 0; db < 8; ++db) {
      float4 bvv = *(const float4*)(b2 + db * 16 + g * 4);
      ushort4 rv = *(const ushort4*)(hrow + db * 16 + g * 4);
      x[db][0] = acc[db][tf][0] + bvv.x + bf2f(rv.x);
      x[db][1] = acc[db][tf][1] + bvv.y + bf2f(rv.y);
      x[db][2] = acc[db][tf][2] + bvv.z + bf2f(rv.z);
      x[db][3] = acc[db][tf][3] + bvv.w + bf2f(rv.w);
#pragma unroll
      for (int r = 0; r < 4; ++r) { s_ += x[db][r]; q_ += x[db][r] * x[db][r]; }
    }
    s_ += __shfl_xor(s_, 16); s_ += __shfl_xor(s_, 32);
    q_ += __shfl_xor(q_, 16); q_ += __shfl_xor(q_, 32);
    float mean = s_ * 0.0078125f;
    float var = q_ * 0.0078125f - mean * mean;
    float rs = rsqrtf(var + 1e-5f);
#pragma unroll
    for (int db = 0; db < 8; ++db) {
      float4 gv = *(const float4*)(gamma + db * 16 + g * 4);
      float4 bb = *(const float4*)(beta + db * 16 + g * 4);
      ushort4 o;
      o.x = f2bf((x[db][0] - mean) * rs * gv.x + bb.x);
      o.y = f2bf((x[db][1] - mean) * rs * gv.y + bb.y);
      o.z = f2bf((x[db][2] - mean) * rs * gv.z + bb.z);
      o.w = f2bf((x[db][3] - mean) * rs * gv.w + bb.w);
      *(ushort4*)(hrow + db * 16 + g * 4) = o;
    }
  }
}

// ---------------------------------------------------------------------------
// Fused vocab projection + entropy, register-transposed, no LDS/barriers.
// ---------------------------------------------------------------------------
__global__ __launch_bounds__(256) void vocab_entropy(
    const unsigned short* __restrict__ h, const unsigned short* __restrict__ Wp,
    const float* __restrict__ bias, float* __restrict__ ent) {
  const int lane = threadIdx.x & 63, w = threadIdx.x >> 6;
  const int c = lane & 15, g = lane >> 4;
  const size_t tok0 = (size_t)blockIdx.x * 128 + w * 32;

  bf16x8 at[2][4];
#pragma unroll
  for (int tf = 0; tf < 2; ++tf)
#pragma unroll
    for (int kk = 0; kk < 4; ++kk)
      at[tf][kk] =
          *(const bf16x8*)(h + (tok0 + tf * 16 + c) * 128 + kk * 32 + g * 8);

  f32x4 acc[16][2] = {};
#pragma unroll
  for (int vb = 0; vb < 16; ++vb)
#pragma unroll
    for (int kk = 0; kk < 4; ++kk) {
      bf16x8 wf = *(const bf16x8*)(Wp + (vb * 4 + kk) * 512 + lane * 8);
      acc[vb][0] = MFMA(wf, at[0][kk], acc[vb][0], 0, 0, 0);
      acc[vb][1] = MFMA(wf, at[1][kk], acc[vb][1], 0, 0, 0);
    }

  const float L2E = 1.4426950408889634f;
#pragma unroll
  for (int tf = 0; tf < 2; ++tf) {
    float m_ = -1e30f;
#pragma unroll
    for (int vb = 0; vb < 16; ++vb) {
      float4 bvv = *(const float4*)(bias + vb * 16 + g * 4);
      acc[vb][tf][0] += bvv.x; acc[vb][tf][1] += bvv.y;
      acc[vb][tf][2] += bvv.z; acc[vb][tf][3] += bvv.w;
      m_ = fmaxf(m_, fmaxf(fmaxf(acc[vb][tf][0], acc[vb][tf][1]),
                           fmaxf(acc[vb][tf][2], acc[vb][tf][3])));
    }
    m_ = fmaxf(m_, __shfl_xor(m_, 16));
    m_ = fmaxf(m_, __shfl_xor(m_, 32));
    float z_ = 0.f, sx_ = 0.f;
#pragma unroll
    for (int vb = 0; vb < 16; ++vb)
#pragma unroll
      for (int r = 0; r < 4; ++r) {
        float xx = acc[vb][tf][r];
        float e = EXP2((xx - m_) * L2E);
        z_ += e; sx_ += e * xx;
      }
    z_ += __shfl_xor(z_, 16);  z_ += __shfl_xor(z_, 32);
    sx_ += __shfl_xor(sx_, 16); sx_ += __shfl_xor(sx_, 32);
    if (g == 0) ent[tok0 + tf * 16 + c] = m_ + logf(z_) - sx_ / z_;
  }
}

// ---------------------------------------------------------------------------
__global__ __launch_bounds__(64) void avg_entropy_kernel(
    const float* __restrict__ ent, float* __restrict__ out) {
  int s = blockIdx.x, lane = threadIdx.x;
  float a = 0.f;
  for (int b = lane; b < 256; b += 64) a += ent[(size_t)b * 512 + s];
#pragma unroll
  for (int off = 32; off; off >>= 1) a += __shfl_xor(a, off);
  if (lane == 0) out[s] = a * 0.00390625f;
}

__global__ __launch_bounds__(512) void seg_kernel(float* out) {
  __shared__ int cs[512];
  int i = threadIdx.x;
  float e = out[i];
  cs[i] = (i >= 1 && e > 4.0f) ? 1 : 0;
  __syncthreads();
  for (int off = 1; off < 512; off <<= 1) {
    int v = (i >= off) ? cs[i - off] : 0;
    __syncthreads();
    cs[i] += v;
    __syncthreads();
  }
  out[512 + i] = (float)cs[i];
}

// ---------------------------------------------------------------------------
extern "C" void kernel_launch(void* const* d_in, const int* in_sizes, int n_in,
                              void* d_out, int out_size, void* d_ws,
                              size_t ws_size, hipStream_t stream) {
  (void)in_sizes; (void)n_in; (void)out_size; (void)ws_size;
  const int*   input_bytes = (const int*)d_in[0];
  const float* emb    = (const float*)d_in[1];
  const float* pos    = (const float*)d_in[2];
  const float* ln_g   = (const float*)d_in[3];
  const float* ln_b   = (const float*)d_in[4];
  const float* attn_w = (const float*)d_in[5];
  const float* attn_b = (const float*)d_in[6];
  const float* out_w  = (const float*)d_in[7];
  const float* out_b  = (const float*)d_in[8];
  const float* ff1_w  = (const float*)d_in[9];
  const float* ff1_b  = (const float*)d_in[10];
  const float* ff2_w  = (const float*)d_in[11];
  const float* ff2_b  = (const float*)d_in[12];
  const float* n1_g   = (const float*)d_in[13];
  const float* n1_b   = (const float*)d_in[14];
  const float* n2_g   = (const float*)d_in[15];
  const float* n2_b   = (const float*)d_in[16];
  const float* proj_w = (const float*)d_in[17];
  const float* proj_b = (const float*)d_in[18];

  char* ws = (char*)d_ws;
  unsigned short* hbf  = (unsigned short*)(ws);                // 32 MB
  unsigned short* obf  = (unsigned short*)(ws + 33554432);     // 32 MB
  unsigned short* wbf  = (unsigned short*)(ws + 67108864);     // ~0.85 MB
  float*          absb = (float*)(ws + 68157440);              // 3 KB
  float*          entb = (float*)(ws + 68161536);              // 0.5 MB

  unsigned short* attnA = wbf;
  unsigned short* outwA = wbf + 98304;
  unsigned short* w1A   = wbf + 131072;
  unsigned short* w2A   = wbf + 262144;
  unsigned short* projA = wbf + 393216;

  conv_attn_headA<<<384, 256, 0, stream>>>(attn_w, attnA);
  conv_attn_b<<<3, 256, 0, stream>>>(attn_b, absb);
  for (int l = 0; l < 2; ++l) {
    conv_permA<<<64, 256, 0, stream>>>(out_w + l * 16384, outwA + l * 16384,
                                       128, 16384);
    conv_permA<<<256, 256, 0, stream>>>(ff1_w + l * 65536, w1A + l * 65536,
                                        128, 65536);
    conv_permA<<<256, 256, 0, stream>>>(ff2_w + l * 65536, w2A + l * 65536,
                                        512, 65536);
  }
  conv_permA<<<128, 256, 0, stream>>>(proj_w, projA, 128, 32768);

  embed_ln<<<32768, 256, 0, stream>>>(input_bytes, emb, pos, ln_g, ln_b, hbf);

  for (int l = 0; l < 2; ++l) {
    attn_fused<<<1024, 512, 0, stream>>>(hbf, attnA + l * 49152,
                                         absb + l * 384, obf);
    oproj_ln<<<1024, 256, 0, stream>>>(obf, outwA + l * 16384, out_b + l * 128,
                                       hbf, n1_g + l * 128, n1_b + l * 128);
    ffn_reg<<<1024, 256, 0, stream>>>(hbf, w1A + l * 65536, ff1_b + l * 512,
                                      w2A + l * 65536, ff2_b + l * 128,
                                      n2_g + l * 128, n2_b + l * 128);
  }

  vocab_entropy<<<1024, 256, 0, stream>>>(hbf, projA, proj_b, entb);
  avg_entropy_kernel<<<512, 64, 0, stream>>>(entb, (float*)d_out);
  seg_kernel<<<1, 512, 0, stream>>>((float*)d_out);
}

// Round 16
// 403.086 us; speedup vs baseline: 1.2727x; 1.0063x over previous
//
#include <hip/hip_runtime.h>

// ---------------------------------------------------------------------------
// EntropyCalculator: 2-layer post-norm transformer encoder + entropy head.
// B=256 S=512 D=128 H=4 HD=32 FF=512 V=256
// Fused QKV+attention (setprio, ones-MFMA l, XCD swizzle);
// fused oproj+LN1+FFN+LN2 via wave-private swizzled LDS (block_tail v2);
// register-transposed vocab/entropy.
// ---------------------------------------------------------------------------

typedef __bf16 bf16x8 __attribute__((ext_vector_type(8)));
typedef float  f32x4  __attribute__((ext_vector_type(4)));

__device__ __forceinline__ unsigned short f2bf(float f) {
  union { float f; unsigned int u; } c; c.f = f;
  unsigned int u = c.u;
  u += 0x7FFFu + ((u >> 16) & 1u);   // round-to-nearest-even
  return (unsigned short)(u >> 16);
}
__device__ __forceinline__ float bf2f(unsigned short u) {
  union { unsigned int u; float f; } c; c.u = ((unsigned int)u) << 16;
  return c.f;
}

__device__ __forceinline__ float EXP2(float x) {
#if __has_builtin(__builtin_amdgcn_exp2f)
  return __builtin_amdgcn_exp2f(x);
#else
  return exp2f(x);
#endif
}

__device__ __forceinline__ unsigned int cvtpk_bf16(float lo, float hi) {
  unsigned int r;
  asm("v_cvt_pk_bf16_f32 %0, %1, %2" : "=v"(r) : "v"(lo), "v"(hi));
  return r;
}
__device__ __forceinline__ void plswap32(unsigned int& a, unsigned int& b) {
  asm("v_permlane32_swap_b32 %0, %1" : "+v"(a), "+v"(b));
}
__device__ __forceinline__ void plswap16(unsigned int& a, unsigned int& b) {
  asm("v_permlane16_swap_b32 %0, %1" : "+v"(a), "+v"(b));
}
// Merge two mfma outputs (rows 0..15 / 16..31 on g*4+reg, col on c) into an
// operand frag: lane(c,g) = M[idx=c][32-dim packed g*8..g*8+7].
__device__ __forceinline__ bf16x8 packfrag(f32x4 a, f32x4 b) {
  unsigned int w00 = cvtpk_bf16(a[0], a[1]), w01 = cvtpk_bf16(a[2], a[3]);
  unsigned int w10 = cvtpk_bf16(b[0], b[1]), w11 = cvtpk_bf16(b[2], b[3]);
  plswap32(w00, w10); plswap16(w00, w10);
  plswap32(w01, w11); plswap16(w01, w11);
  union { unsigned int u[4]; bf16x8 v; } pk;
  pk.u[0] = w00; pk.u[1] = w01; pk.u[2] = w10; pk.u[3] = w11;
  return pk.v;
}

#define MFMA __builtin_amdgcn_mfma_f32_16x16x32_bf16

// ---------------------------------------------------------------------------
// weight conversions
// ---------------------------------------------------------------------------
__global__ void conv_permA(const float* __restrict__ src,
                           unsigned short* __restrict__ dst, int K, int n) {
  int i = blockIdx.x * 256 + threadIdx.x;
  if (i >= n) return;
  int row = i / K, k = i - row * K;
  int frag = (row >> 4) * (K >> 5) + (k >> 5);
  int d = frag * 512 + ((k >> 3) & 3) * 128 + (row & 15) * 8 + (k & 7);
  dst[d] = f2bf(src[i]);
}

// attn_w [2][384][128] -> per (layer, head, mat q/k/v) A-frag arrays of
// 2 db x 4 kk frags (4096 hw each).  Q rows pre-scaled.
#define QSCALE 0.2550602989892646f
__global__ void conv_attn_headA(const float* __restrict__ src,
                                unsigned short* __restrict__ dst) {
  int i = blockIdx.x * 256 + threadIdx.x;  // 98304
  int l = i / 49152, rem = i - l * 49152;
  int row = rem >> 7, k = rem & 127;
  int mat = row >> 7;            // 0=q 1=k 2=v
  int head = (row >> 5) & 3;
  int dr = row & 31;
  float v = src[i];
  if (mat == 0) v *= QSCALE;
  int d = ((l * 4 + head) * 3 + mat) * 4096 +
          ((dr >> 4) * 4 + (k >> 5)) * 512 + ((k >> 3) & 3) * 128 +
          (dr & 15) * 8 + (k & 7);
  dst[d] = f2bf(v);
}
__global__ void conv_attn_b(const float* __restrict__ src,
                            float* __restrict__ dst) {
  int i = blockIdx.x * 256 + threadIdx.x;  // 768
  if (i < 768) {
    float v = src[i];
    if ((i % 384) < 128) v *= QSCALE;
    dst[i] = v;
  }
}

// ---------------------------------------------------------------------------
// Embedding + LayerNorm -> bf16 residual stream.  One wave per token.
// ---------------------------------------------------------------------------
__global__ __launch_bounds__(256) void embed_ln(
    const int* __restrict__ bytes, const float* __restrict__ emb,
    const float* __restrict__ pos, const float* __restrict__ g,
    const float* __restrict__ bta, unsigned short* __restrict__ hbf) {
  int wv = threadIdx.x >> 6, lane = threadIdx.x & 63;
  int tok = blockIdx.x * 4 + wv;
  int s = tok & 511;
  int bidx = bytes[tok];
  const float* e = emb + (size_t)bidx * 128;
  const float* p = pos + (size_t)s * 128;
  float x0 = e[lane] + p[lane];
  float x1 = e[lane + 64] + p[lane + 64];
  float sum = x0 + x1, ssq = x0 * x0 + x1 * x1;
#pragma unroll
  for (int off = 32; off; off >>= 1) {
    sum += __shfl_xor(sum, off);
    ssq += __shfl_xor(ssq, off);
  }
  float mean = sum * 0.0078125f;
  float var = ssq * 0.0078125f - mean * mean;
  float rs = rsqrtf(var + 1e-5f);
  float y0 = (x0 - mean) * rs * g[lane] + bta[lane];
  float y1 = (x1 - mean) * rs * g[lane + 64] + bta[lane + 64];
  size_t o = (size_t)tok * 128;
  hbf[o + lane] = f2bf(y0); hbf[o + lane + 64] = f2bf(y1);
}

// ---------------------------------------------------------------------------
// Fused QKV + flash attention.  s_setprio on MFMA clusters; softmax
// denominator via ones-MFMA; XCD-aware block swizzle.
// One block (512 thr = 8 waves) per (b, head).
// ---------------------------------------------------------------------------
__global__ __launch_bounds__(512)
__attribute__((amdgpu_waves_per_eu(4, 4))) void attn_fused(
    const unsigned short* __restrict__ h, const unsigned short* __restrict__ Wa,
    const float* __restrict__ ab, unsigned short* __restrict__ obf) {
  __shared__ __bf16 Ks[32 * 512];
  __shared__ __bf16 Vt[32 * 512];

  // XCD swizzle: idx = b0 + 8*hh + 32*b1 ; bl = b0 + 8*b1
  const int idx = blockIdx.x;
  const int hh = (idx >> 3) & 3;
  const int bl = (idx & 7) + ((idx >> 5) << 3);
  const int t = threadIdx.x;
  const int lane = t & 63, wv = t >> 6;
  const int c = lane & 15, g = lane >> 4;
  const size_t tok0 = (size_t)bl * 512;
  const size_t myq = tok0 + wv * 64;

  const unsigned short* Wb = Wa + hh * 3 * 4096;
  const float* bq = ab + hh * 32;
  const float* bk = ab + 128 + hh * 32;
  const float* bv = ab + 256 + hh * 32;

  bf16x8 qb[4];
  f32x4 dv[2][2];
#pragma unroll
  for (int tf = 0; tf < 4; ++tf) {
    bf16x8 a4[4];
#pragma unroll
    for (int kk = 0; kk < 4; ++kk)
      a4[kk] =
          *(const bf16x8*)(h + (myq + tf * 16 + c) * 128 + kk * 32 + g * 8);
    // ---- Q ----
    {
      f32x4 d0 = {}, d1 = {};
#pragma unroll
      for (int kk = 0; kk < 4; ++kk) {
        d0 = MFMA(*(const bf16x8*)(Wb + kk * 512 + lane * 8), a4[kk], d0,
                  0, 0, 0);
        d1 = MFMA(*(const bf16x8*)(Wb + (4 + kk) * 512 + lane * 8), a4[kk],
                  d1, 0, 0, 0);
      }
      float4 b0 = *(const float4*)(bq + g * 4);
      float4 b1 = *(const float4*)(bq + 16 + g * 4);
      d0[0] += b0.x; d0[1] += b0.y; d0[2] += b0.z; d0[3] += b0.w;
      d1[0] += b1.x; d1[1] += b1.y; d1[2] += b1.z; d1[3] += b1.w;
      qb[tf] = packfrag(d0, d1);
    }
    // ---- K ----
    {
      f32x4 d0 = {}, d1 = {};
#pragma unroll
      for (int kk = 0; kk < 4; ++kk) {
        d0 = MFMA(*(const bf16x8*)(Wb + 4096 + kk * 512 + lane * 8), a4[kk],
                  d0, 0, 0, 0);
        d1 = MFMA(*(const bf16x8*)(Wb + 4096 + (4 + kk) * 512 + lane * 8),
                  a4[kk], d1, 0, 0, 0);
      }
      float4 b0 = *(const float4*)(bk + g * 4);
      float4 b1 = *(const float4*)(bk + 16 + g * 4);
      d0[0] += b0.x; d0[1] += b0.y; d0[2] += b0.z; d0[3] += b0.w;
      d1[0] += b1.x; d1[1] += b1.y; d1[2] += b1.z; d1[3] += b1.w;
      *(bf16x8*)&Ks[(wv * 4 + tf) * 512 + lane * 8] = packfrag(d0, d1);
    }
    // ---- V ----
#pragma unroll
    for (int hf = 0; hf < 2; ++hf) {
      f32x4 tv = {};
#pragma unroll
      for (int kk = 0; kk < 4; ++kk)
        tv = MFMA(a4[kk],
                  *(const bf16x8*)(Wb + 8192 + (hf * 4 + kk) * 512 + lane * 8),
                  tv, 0, 0, 0);
      float bvv = bv[hf * 16 + c];
      tv[0] += bvv; tv[1] += bvv; tv[2] += bvv; tv[3] += bvv;
      dv[tf & 1][hf] = tv;
    }
    if (tf & 1) {
#pragma unroll
      for (int hf = 0; hf < 2; ++hf)
        *(bf16x8*)&Vt[(hf * 16 + wv * 2 + (tf >> 1)) * 512 + lane * 8] =
            packfrag(dv[0][hf], dv[1][hf]);
    }
  }
  __syncthreads();

  // ones A-frag for l accumulation: out[r][c] = sum_k P^T[k][c] = l(query c)
  bf16x8 onesv;
#pragma unroll
  for (int i = 0; i < 8; ++i) onesv[i] = (__bf16)1.0f;

  f32x4 ot[4][2] = {};
  f32x4 lacc[4] = {};
  const f32x4 zz = {0.f, 0.f, 0.f, 0.f};

  for (int kt = 0; kt < 8; ++kt) {
    bf16x8 ka[4];
#pragma unroll
    for (int kf = 0; kf < 4; ++kf)
      ka[kf] = *(const bf16x8*)&Ks[(kt * 4 + kf) * 512 + lane * 8];
    bf16x8 vb2[2][2];
#pragma unroll
    for (int hf = 0; hf < 2; ++hf)
#pragma unroll
      for (int ksl = 0; ksl < 2; ++ksl)
        vb2[hf][ksl] =
            *(const bf16x8*)&Vt[(hf * 16 + kt * 2 + ksl) * 512 + lane * 8];

#pragma unroll
    for (int qf = 0; qf < 4; ++qf) {
      __builtin_amdgcn_s_setprio(1);
      f32x4 sA = MFMA(ka[0], qb[qf], zz, 0, 0, 0);
      f32x4 sB = MFMA(ka[1], qb[qf], zz, 0, 0, 0);
      f32x4 sC = MFMA(ka[2], qb[qf], zz, 0, 0, 0);
      f32x4 sD = MFMA(ka[3], qb[qf], zz, 0, 0, 0);
      __builtin_amdgcn_s_setprio(0);

      {
        float pa0 = EXP2(sA[0]), pa1 = EXP2(sA[1]);
        float pa2 = EXP2(sA[2]), pa3 = EXP2(sA[3]);
        float pb0 = EXP2(sB[0]), pb1 = EXP2(sB[1]);
        float pb2 = EXP2(sB[2]), pb3 = EXP2(sB[3]);
        f32x4 pa = {pa0, pa1, pa2, pa3};
        f32x4 pb = {pb0, pb1, pb2, pb3};
        bf16x8 pk = packfrag(pa, pb);
        __builtin_amdgcn_s_setprio(1);
        ot[qf][0] = MFMA(vb2[0][0], pk, ot[qf][0], 0, 0, 0);
        ot[qf][1] = MFMA(vb2[1][0], pk, ot[qf][1], 0, 0, 0);
        lacc[qf] = MFMA(onesv, pk, lacc[qf], 0, 0, 0);
        __builtin_amdgcn_s_setprio(0);
      }
      {
        float pa0 = EXP2(sC[0]), pa1 = EXP2(sC[1]);
        float pa2 = EXP2(sC[2]), pa3 = EXP2(sC[3]);
        float pb0 = EXP2(sD[0]), pb1 = EXP2(sD[1]);
        float pb2 = EXP2(sD[2]), pb3 = EXP2(sD[3]);
        f32x4 pa = {pa0, pa1, pa2, pa3};
        f32x4 pb = {pb0, pb1, pb2, pb3};
        bf16x8 pk = packfrag(pa, pb);
        __builtin_amdgcn_s_setprio(1);
        ot[qf][0] = MFMA(vb2[0][1], pk, ot[qf][0], 0, 0, 0);
        ot[qf][1] = MFMA(vb2[1][1], pk, ot[qf][1], 0, 0, 0);
        lacc[qf] = MFMA(onesv, pk, lacc[qf], 0, 0, 0);
        __builtin_amdgcn_s_setprio(0);
      }
    }
  }

#pragma unroll
  for (int qf = 0; qf < 4; ++qf) {
    float rl = 1.0f / lacc[qf][0];   // all 4 rows identical: l for query c
#pragma unroll
    for (int hf = 0; hf < 2; ++hf) {
      ushort4 pk;
      pk.x = f2bf(ot[qf][hf][0] * rl);
      pk.y = f2bf(ot[qf][hf][1] * rl);
      pk.z = f2bf(ot[qf][hf][2] * rl);
      pk.w = f2bf(ot[qf][hf][3] * rl);
      *(ushort4*)(obf + (myq + qf * 16 + c) * 128 + hh * 32 + hf * 16 +
                  g * 4) = pk;
    }
  }
}

// ---------------------------------------------------------------------------
// Fused block tail v2: oproj + residual + LN1 + FFN + residual + LN2.
// LN1 output y lives in wave-private XOR-swizzled LDS (no barriers, acts as
// the transposer for the FFN B-frags and the LN2 residual).  In-place on h.
// 256 thr = 4 waves, wave owns 32 tokens.  LDS 32 KB.
// ---------------------------------------------------------------------------
__global__ __launch_bounds__(256) void block_tail(
    const unsigned short* __restrict__ A,    // attention output (obf)
    const unsigned short* __restrict__ Wo, const float* __restrict__ bo,
    const float* __restrict__ g1, const float* __restrict__ b1n,
    const unsigned short* __restrict__ W1p, const float* __restrict__ b1,
    const unsigned short* __restrict__ W2p, const float* __restrict__ b2,
    const float* __restrict__ g2, const float* __restrict__ b2n,
    unsigned short* __restrict__ h) {
  __shared__ char Ylds[4 * 8192];
  const int lane = threadIdx.x & 63, w = threadIdx.x >> 6;
  const int c = lane & 15, g = lane >> 4;
  const size_t tok0 = (size_t)blockIdx.x * 128 + w * 32;
  char* yb = Ylds + w * 8192;   // wave-private [32 tok][128 col] swizzled

  // ---- out-proj ----
  f32x4 acc[8][2] = {};
  {
    bf16x8 at[2][4];
#pragma unroll
    for (int tf = 0; tf < 2; ++tf)
#pragma unroll
      for (int kk = 0; kk < 4; ++kk)
        at[tf][kk] =
            *(const bf16x8*)(A + (tok0 + tf * 16 + c) * 128 + kk * 32 + g * 8);
#pragma unroll
    for (int db = 0; db < 8; ++db)
#pragma unroll
      for (int kk = 0; kk < 4; ++kk) {
        bf16x8 wf = *(const bf16x8*)(Wo + (db * 4 + kk) * 512 + lane * 8);
        acc[db][0] = MFMA(wf, at[0][kk], acc[db][0], 0, 0, 0);
        acc[db][1] = MFMA(wf, at[1][kk], acc[db][1], 0, 0, 0);
      }
  }

  // ---- residual + LN1 -> y in LDS ----
#pragma unroll
  for (int tf = 0; tf < 2; ++tf) {
    const unsigned short* hrow = h + (tok0 + tf * 16 + c) * 128;
    float x[8][4];
    float s_ = 0.f, q_ = 0.f;
#pragma unroll
    for (int db = 0; db < 8; ++db) {
      float4 bvv = *(const float4*)(bo + db * 16 + g * 4);
      ushort4 rv = *(const ushort4*)(hrow + db * 16 + g * 4);
      x[db][0] = acc[db][tf][0] + bvv.x + bf2f(rv.x);
      x[db][1] = acc[db][tf][1] + bvv.y + bf2f(rv.y);
      x[db][2] = acc[db][tf][2] + bvv.z + bf2f(rv.z);
      x[db][3] = acc[db][tf][3] + bvv.w + bf2f(rv.w);
#pragma unroll
      for (int r = 0; r < 4; ++r) { s_ += x[db][r]; q_ += x[db][r] * x[db][r]; }
    }
    s_ += __shfl_xor(s_, 16); s_ += __shfl_xor(s_, 32);
    q_ += __shfl_xor(q_, 16); q_ += __shfl_xor(q_, 32);
    float mean = s_ * 0.0078125f;
    float var = q_ * 0.0078125f - mean * mean;
    float rs = rsqrtf(var + 1e-5f);
    int tok = tf * 16 + c;
#pragma unroll
    for (int db = 0; db < 8; ++db) {
      float4 gv = *(const float4*)(g1 + db * 16 + g * 4);
      float4 bb = *(const float4*)(b1n + db * 16 + g * 4);
      float y0 = (x[db][0] - mean) * rs * gv.x + bb.x;
      float y1 = (x[db][1] - mean) * rs * gv.y + bb.y;
      float y2 = (x[db][2] - mean) * rs * gv.z + bb.z;
      float y3 = (x[db][3] - mean) * rs * gv.w + bb.w;
      uint2 pp;
      pp.x = cvtpk_bf16(y0, y1);
      pp.y = cvtpk_bf16(y2, y3);
      int ch = (db * 2 + (g >> 1)) ^ c;
      *(uint2*)(yb + tok * 256 + ch * 16 + (g & 1) * 8) = pp;
    }
  }

  // ---- FFN B-frags from LDS (the swizzled read IS the transpose) ----
  bf16x8 at2[2][4];
#pragma unroll
  for (int tf = 0; tf < 2; ++tf) {
    int tok = tf * 16 + c;
#pragma unroll
    for (int kk = 0; kk < 4; ++kk) {
      int ch = (kk * 4 + g) ^ c;
      at2[tf][kk] = *(const bf16x8*)(yb + tok * 256 + ch * 16);
    }
  }

  // ---- FFN (G register-resident) ----
  f32x4 acc2[8][2] = {};
  for (int s = 0; s < 16; ++s) {
    f32x4 d1[2][2] = {};
#pragma unroll
    for (int kk = 0; kk < 4; ++kk) {
      bf16x8 wa = *(const bf16x8*)(W1p + ((2 * s) * 4 + kk) * 512 + lane * 8);
      bf16x8 wb = *(const bf16x8*)(W1p + ((2 * s + 1) * 4 + kk) * 512 + lane * 8);
      d1[0][0] = MFMA(wa, at2[0][kk], d1[0][0], 0, 0, 0);
      d1[0][1] = MFMA(wa, at2[1][kk], d1[0][1], 0, 0, 0);
      d1[1][0] = MFMA(wb, at2[0][kk], d1[1][0], 0, 0, 0);
      d1[1][1] = MFMA(wb, at2[1][kk], d1[1][1], 0, 0, 0);
    }
    float4 bva = *(const float4*)(b1 + s * 32 + g * 4);
    float4 bvb = *(const float4*)(b1 + s * 32 + 16 + g * 4);
    bf16x8 gp[2];
#pragma unroll
    for (int tf = 0; tf < 2; ++tf) {
      f32x4 pa, pb;
      pa[0] = fmaxf(d1[0][tf][0] + bva.x, 0.f);
      pa[1] = fmaxf(d1[0][tf][1] + bva.y, 0.f);
      pa[2] = fmaxf(d1[0][tf][2] + bva.z, 0.f);
      pa[3] = fmaxf(d1[0][tf][3] + bva.w, 0.f);
      pb[0] = fmaxf(d1[1][tf][0] + bvb.x, 0.f);
      pb[1] = fmaxf(d1[1][tf][1] + bvb.y, 0.f);
      pb[2] = fmaxf(d1[1][tf][2] + bvb.z, 0.f);
      pb[3] = fmaxf(d1[1][tf][3] + bvb.w, 0.f);
      gp[tf] = packfrag(pa, pb);
    }
#pragma unroll
    for (int db = 0; db < 8; ++db) {
      bf16x8 w2 = *(const bf16x8*)(W2p + (db * 16 + s) * 512 + lane * 8);
      acc2[db][0] = MFMA(w2, gp[0], acc2[db][0], 0, 0, 0);
      acc2[db][1] = MFMA(w2, gp[1], acc2[db][1], 0, 0, 0);
    }
  }

  // ---- residual (y from LDS) + LN2 -> h ----
#pragma unroll
  for (int tf = 0; tf < 2; ++tf) {
    unsigned short* hrow = h + (tok0 + tf * 16 + c) * 128;
    int tok = tf * 16 + c;
    float x[8][4];
    float s_ = 0.f, q_ = 0.f;
#pragma unroll
    for (int db = 0; db < 8; ++db) {
      float4 bvv = *(const float4*)(b2 + db * 16 + g * 4);
      int ch = (db * 2 + (g >> 1)) ^ c;
      uint2 pp = *(const uint2*)(yb + tok * 256 + ch * 16 + (g & 1) * 8);
      x[db][0] = acc2[db][tf][0] + bvv.x + bf2f((unsigned short)pp.x);
      x[db][1] = acc2[db][tf][1] + bvv.y + bf2f((unsigned short)(pp.x >> 16));
      x[db][2] = acc2[db][tf][2] + bvv.z + bf2f((unsigned short)pp.y);
      x[db][3] = acc2[db][tf][3] + bvv.w + bf2f((unsigned short)(pp.y >> 16));
#pragma unroll
      for (int r = 0; r < 4; ++r) { s_ += x[db][r]; q_ += x[db][r] * x[db][r]; }
    }
    s_ += __shfl_xor(s_, 16); s_ += __shfl_xor(s_, 32);
    q_ += __shfl_xor(q_, 16); q_ += __shfl_xor(q_, 32);
    float mean = s_ * 0.0078125f;
    float var = q_ * 0.0078125f - mean * mean;
    float rs = rsqrtf(var + 1e-5f);
#pragma unroll
    for (int db = 0; db < 8; ++db) {
      float4 gv = *(const float4*)(g2 + db * 16 + g * 4);
      float4 bb = *(const float4*)(b2n + db * 16 + g * 4);
      ushort4 o;
      o.x = f2bf((x[db][0] - mean) * rs * gv.x + bb.x);
      o.y = f2bf((x[db][1] - mean) * rs * gv.y + bb.y);
      o.z = f2bf((x[db][2] - mean) * rs * gv.z + bb.z);
      o.w = f2bf((x[db][3] - mean) * rs * gv.w + bb.w);
      *(ushort4*)(hrow + db * 16 + g * 4) = o;
    }
  }
}

// ---------------------------------------------------------------------------
// Fused vocab projection + entropy, register-transposed, no LDS/barriers.
// ---------------------------------------------------------------------------
__global__ __launch_bounds__(256) void vocab_entropy(
    const unsigned short* __restrict__ h, const unsigned short* __restrict__ Wp,
    const float* __restrict__ bias, float* __restrict__ ent) {
  const int lane = threadIdx.x & 63, w = threadIdx.x >> 6;
  const int c = lane & 15, g = lane >> 4;
  const size_t tok0 = (size_t)blockIdx.x * 128 + w * 32;

  bf16x8 at[2][4];
#pragma unroll
  for (int tf = 0; tf < 2; ++tf)
#pragma unroll
    for (int kk = 0; kk < 4; ++kk)
      at[tf][kk] =
          *(const bf16x8*)(h + (tok0 + tf * 16 + c) * 128 + kk * 32 + g * 8);

  f32x4 acc[16][2] = {};
#pragma unroll
  for (int vb = 0; vb < 16; ++vb)
#pragma unroll
    for (int kk = 0; kk < 4; ++kk) {
      bf16x8 wf = *(const bf16x8*)(Wp + (vb * 4 + kk) * 512 + lane * 8);
      acc[vb][0] = MFMA(wf, at[0][kk], acc[vb][0], 0, 0, 0);
      acc[vb][1] = MFMA(wf, at[1][kk], acc[vb][1], 0, 0, 0);
    }

  const float L2E = 1.4426950408889634f;
#pragma unroll
  for (int tf = 0; tf < 2; ++tf) {
    float m_ = -1e30f;
#pragma unroll
    for (int vb = 0; vb < 16; ++vb) {
      float4 bvv = *(const float4*)(bias + vb * 16 + g * 4);
      acc[vb][tf][0] += bvv.x; acc[vb][tf][1] += bvv.y;
      acc[vb][tf][2] += bvv.z; acc[vb][tf][3] += bvv.w;
      m_ = fmaxf(m_, fmaxf(fmaxf(acc[vb][tf][0], acc[vb][tf][1]),
                           fmaxf(acc[vb][tf][2], acc[vb][tf][3])));
    }
    m_ = fmaxf(m_, __shfl_xor(m_, 16));
    m_ = fmaxf(m_, __shfl_xor(m_, 32));
    float z_ = 0.f, sx_ = 0.f;
#pragma unroll
    for (int vb = 0; vb < 16; ++vb)
#pragma unroll
      for (int r = 0; r < 4; ++r) {
        float xx = acc[vb][tf][r];
        float e = EXP2((xx - m_) * L2E);
        z_ += e; sx_ += e * xx;
      }
    z_ += __shfl_xor(z_, 16);  z_ += __shfl_xor(z_, 32);
    sx_ += __shfl_xor(sx_, 16); sx_ += __shfl_xor(sx_, 32);
    if (g == 0) ent[tok0 + tf * 16 + c] = m_ + logf(z_) - sx_ / z_;
  }
}

// ---------------------------------------------------------------------------
__global__ __launch_bounds__(64) void avg_entropy_kernel(
    const float* __restrict__ ent, float* __restrict__ out) {
  int s = blockIdx.x, lane = threadIdx.x;
  float a = 0.f;
  for (int b = lane; b < 256; b += 64) a += ent[(size_t)b * 512 + s];
#pragma unroll
  for (int off = 32; off; off >>= 1) a += __shfl_xor(a, off);
  if (lane == 0) out[s] = a * 0.00390625f;
}

__global__ __launch_bounds__(512) void seg_kernel(float* out) {
  __shared__ int cs[512];
  int i = threadIdx.x;
  float e = out[i];
  cs[i] = (i >= 1 && e > 4.0f) ? 1 : 0;
  __syncthreads();
  for (int off = 1; off < 512; off <<= 1) {
    int v = (i >= off) ? cs[i - off] : 0;
    __syncthreads();
    cs[i] += v;
    __syncthreads();
  }
  out[512 + i] = (float)cs[i];
}

// ---------------------------------------------------------------------------
extern "C" void kernel_launch(void* const* d_in, const int* in_sizes, int n_in,
                              void* d_out, int out_size, void* d_ws,
                              size_t ws_size, hipStream_t stream) {
  (void)in_sizes; (void)n_in; (void)out_size; (void)ws_size;
  const int*   input_bytes = (const int*)d_in[0];
  const float* emb    = (const float*)d_in[1];
  const float* pos    = (const float*)d_in[2];
  const float* ln_g   = (const float*)d_in[3];
  const float* ln_b   = (const float*)d_in[4];
  const float* attn_w = (const float*)d_in[5];
  const float* attn_b = (const float*)d_in[6];
  const float* out_w  = (const float*)d_in[7];
  const float* out_b  = (const float*)d_in[8];
  const float* ff1_w  = (const float*)d_in[9];
  const float* ff1_b  = (const float*)d_in[10];
  const float* ff2_w  = (const float*)d_in[11];
  const float* ff2_b  = (const float*)d_in[12];
  const float* n1_g   = (const float*)d_in[13];
  const float* n1_b   = (const float*)d_in[14];
  const float* n2_g   = (const float*)d_in[15];
  const float* n2_b   = (const float*)d_in[16];
  const float* proj_w = (const float*)d_in[17];
  const float* proj_b = (const float*)d_in[18];

  char* ws = (char*)d_ws;
  unsigned short* hbf  = (unsigned short*)(ws);                // 32 MB
  unsigned short* obf  = (unsigned short*)(ws + 33554432);     // 32 MB
  unsigned short* wbf  = (unsigned short*)(ws + 67108864);     // ~0.85 MB
  float*          absb = (float*)(ws + 68157440);              // 3 KB
  float*          entb = (float*)(ws + 68161536);              // 0.5 MB

  unsigned short* attnA = wbf;
  unsigned short* outwA = wbf + 98304;
  unsigned short* w1A   = wbf + 131072;
  unsigned short* w2A   = wbf + 262144;
  unsigned short* projA = wbf + 393216;

  conv_attn_headA<<<384, 256, 0, stream>>>(attn_w, attnA);
  conv_attn_b<<<3, 256, 0, stream>>>(attn_b, absb);
  for (int l = 0; l < 2; ++l) {
    conv_permA<<<64, 256, 0, stream>>>(out_w + l * 16384, outwA + l * 16384,
                                       128, 16384);
    conv_permA<<<256, 256, 0, stream>>>(ff1_w + l * 65536, w1A + l * 65536,
                                        128, 65536);
    conv_permA<<<256, 256, 0, stream>>>(ff2_w + l * 65536, w2A + l * 65536,
                                        512, 65536);
  }
  conv_permA<<<128, 256, 0, stream>>>(proj_w, projA, 128, 32768);

  embed_ln<<<32768, 256, 0, stream>>>(input_bytes, emb, pos, ln_g, ln_b, hbf);

  for (int l = 0; l < 2; ++l) {
    attn_fused<<<1024, 512, 0, stream>>>(hbf, attnA + l * 49152,
                                         absb + l * 384, obf);
    block_tail<<<1024, 256, 0, stream>>>(
        obf, outwA + l * 16384, out_b + l * 128, n1_g + l * 128,
        n1_b + l * 128, w1A + l * 65536, ff1_b + l * 512, w2A + l * 65536,
        ff2_b + l * 128, n2_g + l * 128, n2_b + l * 128, hbf);
  }

  vocab_entropy<<<1024, 256, 0, stream>>>(hbf, projA, proj_b, entb);
  avg_entropy_kernel<<<512, 64, 0, stream>>>(entb, (float*)d_out);
  seg_kernel<<<1, 512, 0, stream>>>((float*)d_out);
}